// Round 12
// baseline (642.977 us; speedup 1.0000x reference)
//
#include <hip/hip_runtime.h>
#include <cmath>

using f16x8  = __attribute__((ext_vector_type(8))) _Float16;
using f32x16 = __attribute__((ext_vector_type(16))) float;

// ---------- helpers ----------
__device__ __forceinline__ void gld16(void* lds, const void* g) {
    __builtin_amdgcn_global_load_lds(
        (const __attribute__((address_space(1))) unsigned int*)g,
        (__attribute__((address_space(3))) unsigned int*)lds, 16, 0, 0);
}

// ========= Layouts =========
// K_eff = 2048: k_eff = 2k + s, s=0 -> f16-hi(x), s=1 -> f16-lo residual.
// W_eff[2k+s][u] = w[k][u] (duplicated) so a SINGLE f16 MFMA chain computes
// hi*w + lo*w (2-product split numerics).
//
// A-blob: per (mt, kt) 32KB: 256 m-rows x 128B (64 k_eff).  Row r, stored
// 16B slot sh holds k_eff octet qe = sh ^ (r&7) (pre-swizzled image).
// W-blob: per (nt12, kt) 32KB, same swizzle, w duplicated along k_eff.
// Linear global_load_lds reproduces the swizzled image; ds_read_b128 at
// slot ((ks*2+lhi)^(row&7)) is 2-way (free).  kt strides padded to 33.

// ---------- convert x -> A blob ----------
__global__ __launch_bounds__(256)
void bru_conv_a(const float* __restrict__ x, char* __restrict__ Ablob,
                int T, int D, int Tc, int t0, int Mc)
{
    const int gid = blockIdx.x * 256 + threadIdx.x;   // Mc*32 threads
    const int kt = gid / Mc;
    const int m  = gid - kt * Mc;
    const int mt = m >> 8, row = m & 255;

    const long xrow = (long)(m / Tc) * T + t0 + (m % Tc);
    const float* src = x + xrow * (long)D + kt * 32;

    float v[32];
    #pragma unroll
    for (int i = 0; i < 8; ++i)
        *(float4*)&v[i * 4] = *(const float4*)(src + i * 4);

    _Float16 hi[32], lo[32];
    #pragma unroll
    for (int k = 0; k < 32; ++k) {
        hi[k] = (_Float16)v[k];
        lo[k] = (_Float16)(v[k] - (float)hi[k]);
    }

    char* base = Ablob + ((size_t)(mt * 33 + kt)) * 32768 + (size_t)row * 128;
    #pragma unroll
    for (int qe = 0; qe < 8; ++qe) {
        _Float16 o[8];
        #pragma unroll
        for (int j = 0; j < 8; ++j) {
            const int k = qe * 4 + (j >> 1);
            o[j] = (j & 1) ? lo[k] : hi[k];
        }
        *(f16x8*)(base + ((qe ^ (row & 7)) << 4)) = *(f16x8*)o;
    }
}

// ---------- convert W (3 gates) -> W_eff blobs (duplicated along K) ----------
__global__ __launch_bounds__(256)
void bru_conv_w(const float* __restrict__ wz, const float* __restrict__ wr,
                const float* __restrict__ wh, char* __restrict__ Wblob,
                int D, int U)
{
    const int gid  = blockIdx.x * 256 + threadIdx.x;  // 12*32*2048 threads
    const int blob = gid >> 11;
    const int idx  = gid & 2047;
    const int qe   = idx >> 8;            // 0..7
    const int row  = idx & 255;           // consecutive -> coalesced u

    const int nt12 = blob >> 5;
    const int kt   = blob & 31;
    const int g    = nt12 >> 2;
    const int ntl  = nt12 & 3;

    const float* W = (g == 0) ? wz : (g == 1) ? wr : wh;
    const int ucol = ntl * 256 + row;

    _Float16 wf[4];
    #pragma unroll
    for (int jj = 0; jj < 4; ++jj)
        wf[jj] = (_Float16)W[(long)(kt * 32 + qe * 4 + jj) * U + ucol];

    _Float16 o[8];
    #pragma unroll
    for (int j = 0; j < 8; ++j) o[j] = wf[j >> 1];

    *(f16x8*)(Wblob + ((size_t)(nt12 * 33 + kt)) * 32768 + (size_t)row * 128
              + ((qe ^ (row & 7)) << 4)) = *(f16x8*)o;
}

// ---------- f16 MFMA GEMM over K_eff=2048, phase-pinned LDS schedule ----------
// Block 256x256; 8 waves 2x4, wave tile 128m x 64n, 32x32x16_f16.
// Per kt: 2 sub-phases, each {12 ds_read burst; 4 gld16; barrier; lgkmcnt(0);
// setprio(1); 16 MFMA; setprio(0); barrier} -> ds_reads are pinned into a
// tight post-barrier burst, so the async staging writes land in the
// LDS-quiet MFMA windows (kills the read<->write bank-conflict tax seen as
// SQ_LDS_BANK_CONFLICT=3.775e7 whenever staging overlapped spread-out reads).
__global__ __launch_bounds__(512, 2)
void bru_gemm_mfma(const char* __restrict__ Ablob, const char* __restrict__ Wblob,
                   const float* __restrict__ bz, const float* __restrict__ br,
                   const float* __restrict__ bh,
                   _Float16* __restrict__ proj,
                   int nmt, int U, int Mc)
{
    __shared__ char sm[131072];   // [2 buf][A 32KB | B 32KB]

    const int ngrid = gridDim.x;
    const int bid   = blockIdx.x;
    int lid = bid;
    if ((ngrid & 7) == 0) lid = (bid & 7) * (ngrid >> 3) + (bid >> 3);
    const int mt   = lid / 12;
    const int nt12 = lid - mt * 12;
    const int g    = nt12 >> 2;
    const int ntl  = nt12 & 3;

    const int tid  = threadIdx.x;
    const int lane = tid & 63;
    const int w    = tid >> 6;
    const int wm   = w >> 2, wn = w & 3;   // 2x4 wave grid; wave tile 128x64
    const int l31  = lane & 31;
    const int lhi  = lane >> 5;
    const int r7   = l31 & 7;

    const char* asrc = Ablob + (size_t)(mt * 33) * 32768;
    const char* bsrc = Wblob + (size_t)(nt12 * 33) * 32768;

    const int abase = (wm * 128 + l31) * 128;            // + i*32*128
    const int bbase = 32768 + (wn * 64 + l31) * 128;     // + j*32*128

    f32x16 acc[4][2];
    #pragma unroll
    for (int i = 0; i < 4; ++i)
        #pragma unroll
        for (int j = 0; j < 2; ++j) acc[i][j] = (f32x16)0.f;

    // prologue: stage kt=0 into buf0
    #pragma unroll
    for (int c = 0; c < 4; ++c) {
        gld16(sm + c * 8192 + tid * 16,         asrc + c * 8192 + tid * 16);
        gld16(sm + 32768 + c * 8192 + tid * 16, bsrc + c * 8192 + tid * 16);
    }
    __syncthreads();

    for (int kt = 0; kt < 32; ++kt) {
        const int cur = (kt & 1) << 16;
        char* nxt = sm + (cur ^ 65536);
        const char* an = asrc + (size_t)(kt + 1) * 32768;
        const char* bn = bsrc + (size_t)(kt + 1) * 32768;
        const char* smc = sm + cur;

        #pragma unroll
        for (int sp = 0; sp < 2; ++sp) {
            // 12-read burst for ksteps {2sp, 2sp+1}
            f16x8 af[2][4], bf[2][2];
            #pragma unroll
            for (int k2 = 0; k2 < 2; ++k2) {
                const int slot = (((sp * 2 + k2) * 2 + lhi) ^ r7) << 4;
                #pragma unroll
                for (int i = 0; i < 4; ++i)
                    af[k2][i] = *(const f16x8*)(smc + abase + i * 4096 + slot);
                #pragma unroll
                for (int j = 0; j < 2; ++j)
                    bf[k2][j] = *(const f16x8*)(smc + bbase + j * 4096 + slot);
            }
            // stage half of kt+1 (A at sp0, B at sp1); writes land during
            // the following MFMA windows (kt=31 stages pad; never read)
            if (sp == 0) {
                #pragma unroll
                for (int c = 0; c < 4; ++c)
                    gld16(nxt + c * 8192 + tid * 16, an + c * 8192 + tid * 16);
            } else {
                #pragma unroll
                for (int c = 0; c < 4; ++c)
                    gld16(nxt + 32768 + c * 8192 + tid * 16, bn + c * 8192 + tid * 16);
            }
            __builtin_amdgcn_s_barrier();
            asm volatile("s_waitcnt lgkmcnt(0)" ::: "memory");
            __builtin_amdgcn_sched_barrier(0);
            __builtin_amdgcn_s_setprio(1);
            #pragma unroll
            for (int k2 = 0; k2 < 2; ++k2)
                #pragma unroll
                for (int i = 0; i < 4; ++i)
                    #pragma unroll
                    for (int j = 0; j < 2; ++j)
                        acc[i][j] = __builtin_amdgcn_mfma_f32_32x32x16_f16(
                            af[k2][i], bf[k2][j], acc[i][j], 0, 0, 0);
            __builtin_amdgcn_s_setprio(0);
            __builtin_amdgcn_s_barrier();
        }

        __syncthreads();   // drain this kt's stages; swap buffers
    }

    // epilogue: C map (verified): col=lane&31, row=(reg&3)+8*(reg>>2)+4*(lane>>5)
    const float* bias = (g == 0) ? bz : (g == 1) ? br : bh;
    const int n0 = ntl * 256 + wn * 64;
    float bcol[2];
    #pragma unroll
    for (int j = 0; j < 2; ++j) bcol[j] = bias[n0 + j * 32 + l31];

    _Float16* cbase = proj + (size_t)g * Mc * U + (size_t)n0 + l31;
    #pragma unroll
    for (int i = 0; i < 4; ++i) {
        #pragma unroll
        for (int j = 0; j < 2; ++j) {
            #pragma unroll
            for (int reg = 0; reg < 16; ++reg) {
                const int row = mt * 256 + wm * 128 + i * 32
                              + (reg & 3) + 8 * (reg >> 2) + 4 * lhi;
                cbase[(size_t)row * U + j * 32] = (_Float16)(acc[i][j][reg] + bcol[j]);
            }
        }
    }
}

// ---------- scan: one thread per (b,u); 8-deep rotating register prefetch ----------
#define PF 8
__global__ __launch_bounds__(256)
void bru_scan(const _Float16* __restrict__ proj,
              const float* __restrict__ mz, const float* __restrict__ mr,
              float* __restrict__ out,
              float* __restrict__ hstate,
              int B, int T, int U, int Tc, int t0, int Mc)
{
    const int idx = blockIdx.x * blockDim.x + threadIdx.x;
    const int b = idx / U;
    const int u = idx - b * U;

    float h = (t0 == 0) ? 0.f : hstate[idx];
    const float vmz = mz[u];
    const float vmr = mr[u];

    const _Float16* pz = proj + (long)b * Tc * U + u;
    const _Float16* pr = pz + (long)Mc * U;
    const _Float16* ph = pr + (long)Mc * U;
    float* po = out + ((long)b * T + t0) * U + u;

    _Float16 fz[PF], fr[PF], fh[PF];
    #pragma unroll
    for (int i = 0; i < PF; ++i) {
        const long o = (long)((i < Tc) ? i : (Tc - 1)) * U;
        fz[i] = pz[o]; fr[i] = pr[o]; fh[i] = ph[o];
    }

    for (int t = 0; t < Tc; t += PF) {
        #pragma unroll
        for (int i = 0; i < PF; ++i) {
            const float xz = (float)fz[i];
            const float xr = (float)fr[i];
            const float xh = (float)fh[i];
            {
                int tn = t + i + PF; if (tn > Tc - 1) tn = Tc - 1;
                const long o = (long)tn * U;
                fz[i] = pz[o]; fr[i] = pr[o]; fh[i] = ph[o];
            }
            const float e2r = __expf(2.f * (xr + h * vmr));
            const float rr  = 2.f - 2.f / (e2r + 1.f);             // tanh(.)+1
            const float zz  = 1.f / (1.f + __expf(-(xz + h * vmz)));
            const float e2h = __expf(2.f * (xh + rr * h));
            const float hh  = 1.f - 2.f / (e2h + 1.f);             // tanh(.)
            h = (1.f - zz) * hh + zz * h;
            if (t + i < Tc) po[(long)(t + i) * U] = h;
        }
    }
    hstate[idx] = h;
}

// ---------- launch ----------
extern "C" void kernel_launch(void* const* d_in, const int* in_sizes, int n_in,
                              void* d_out, int out_size, void* d_ws, size_t ws_size,
                              hipStream_t stream)
{
    const float* x  = (const float*)d_in[0];
    const float* wz = (const float*)d_in[1];
    const float* wr = (const float*)d_in[2];
    const float* wh = (const float*)d_in[3];
    const float* mz = (const float*)d_in[4];
    const float* mr = (const float*)d_in[5];
    const float* bz = (const float*)d_in[6];
    const float* br = (const float*)d_in[7];
    const float* bh = (const float*)d_in[8];

    const int B = 64, T = 512, D = 1024, U = 1024;

    const size_t h_bytes = (size_t)B * U * sizeof(float);
    const size_t w_bytes = (size_t)12 * 33 * 32768;   // 12.98 MB incl. pad

    int Tc = T;
    while (Tc > 4) {
        const int nmt_ = B * Tc / 256;
        const size_t a_bytes_ = (size_t)nmt_ * 33 * 32768;
        const size_t p_bytes_ = 3ull * B * Tc * U * sizeof(_Float16);
        if (h_bytes + w_bytes + a_bytes_ + p_bytes_ <= ws_size) break;
        Tc >>= 1;
    }
    const int nmt = B * Tc / 256;
    const int Mc  = B * Tc;
    const size_t a_bytes = (size_t)nmt * 33 * 32768;

    float*    h_state = (float*)d_ws;
    char*     Wblob   = (char*)d_ws + h_bytes;
    char*     Ablob   = (char*)d_ws + h_bytes + w_bytes;
    _Float16* proj    = (_Float16*)((char*)d_ws + h_bytes + w_bytes + a_bytes);

    bru_conv_w<<<12 * 32 * 2048 / 256, 256, 0, stream>>>(wz, wr, wh, Wblob, D, U);

    for (int t0 = 0; t0 < T; t0 += Tc) {
        bru_conv_a<<<(Mc * 32) / 256, 256, 0, stream>>>(x, Ablob, T, D, Tc, t0, Mc);

        bru_gemm_mfma<<<3 * nmt * 4, 512, 0, stream>>>(
            Ablob, Wblob, bz, br, bh, proj, nmt, U, Mc);

        bru_scan<<<(B * U) / 256, 256, 0, stream>>>(
            proj, mz, mr, (float*)d_out, h_state, B, T, U, Tc, t0, Mc);
    }
}

// Round 13
// 631.668 us; speedup vs baseline: 1.0179x; 1.0179x over previous
//
#include <hip/hip_runtime.h>
#include <cmath>

using f16x8 = __attribute__((ext_vector_type(8))) _Float16;
using f32x4 = __attribute__((ext_vector_type(4))) float;

// ---------- helpers ----------
__device__ __forceinline__ void gld16(void* lds, const void* g) {
    __builtin_amdgcn_global_load_lds(
        (const __attribute__((address_space(1))) unsigned int*)g,
        (__attribute__((address_space(3))) unsigned int*)lds, 16, 0, 0);
}

// ========= Layouts =========
// K_eff = 2048: k_eff = 2k + s; s=0 -> f16-hi(x), s=1 -> f16-lo residual.
// W_eff[2k+s][u] = w[k][u] (duplicated) -> one f16 MFMA chain = hi*w + lo*w.
//
// A-blob: per (mt128, kt) 16KB: 128 m-rows x 128B (64 k_eff).  Row r, stored
//   16B slot sh holds k_eff octet qe = sh ^ (r&7) (pre-swizzled image).
// W-blob: per (g, nt128, kt) 16KB: 128 u-rows x 128B, same swizzle, w dup'd.
// Linear global_load_lds reproduces the swizzled image.  Fragment reads use
// the round-2 geometry (rows = lane&15 groups, slot (ks*4+lgrp)^(row&7))
// which measured ZERO SQ_LDS_BANK_CONFLICT; staging is fully drained before
// any read (r2 discipline), so no write is ever in flight during reads.

// ---------- convert x -> A blob ----------
__global__ __launch_bounds__(256)
void bru_conv_a(const float* __restrict__ x, char* __restrict__ Ablob,
                int T, int D, int Tc, int t0, int Mc)
{
    const int gid = blockIdx.x * 256 + threadIdx.x;   // Mc*32 threads
    const int kt = gid / Mc;
    const int m  = gid - kt * Mc;
    const int mt = m >> 7, row = m & 127;

    const long xrow = (long)(m / Tc) * T + t0 + (m % Tc);
    const float* src = x + xrow * (long)D + kt * 32;

    float v[32];
    #pragma unroll
    for (int i = 0; i < 8; ++i)
        *(float4*)&v[i * 4] = *(const float4*)(src + i * 4);

    _Float16 hi[32], lo[32];
    #pragma unroll
    for (int k = 0; k < 32; ++k) {
        hi[k] = (_Float16)v[k];
        lo[k] = (_Float16)(v[k] - (float)hi[k]);
    }

    char* base = Ablob + ((size_t)(mt * 32 + kt)) * 16384 + (size_t)row * 128;
    #pragma unroll
    for (int qe = 0; qe < 8; ++qe) {
        _Float16 o[8];
        #pragma unroll
        for (int j = 0; j < 8; ++j) {
            const int k = qe * 4 + (j >> 1);
            o[j] = (j & 1) ? lo[k] : hi[k];
        }
        *(f16x8*)(base + ((qe ^ (row & 7)) << 4)) = *(f16x8*)o;
    }
}

// ---------- convert W (3 gates) -> W_eff blobs ----------
__global__ __launch_bounds__(256)
void bru_conv_w(const float* __restrict__ wz, const float* __restrict__ wr,
                const float* __restrict__ wh, char* __restrict__ Wblob,
                int D, int U)
{
    const int gid  = blockIdx.x * 256 + threadIdx.x;  // 768*1024 threads
    const int blob = gid >> 10;           // (g*8+nt)*32 + kt
    const int idx  = gid & 1023;
    const int row  = idx >> 3;            // u within 128-col tile
    const int s    = idx & 7;

    const int g    = blob >> 8;           // 8 nt * 32 kt = 256 per gate
    const int rest = blob & 255;
    const int nt   = rest >> 5;
    const int kt   = rest & 31;

    const float* W = (g == 0) ? wz : (g == 1) ? wr : wh;
    const int qe   = s ^ (row & 7);
    const int ucol = nt * 128 + row;

    _Float16 wf[4];
    #pragma unroll
    for (int jj = 0; jj < 4; ++jj)
        wf[jj] = (_Float16)W[(long)(kt * 32 + qe * 4 + jj) * U + ucol];

    _Float16 o[8];
    #pragma unroll
    for (int j = 0; j < 8; ++j) o[j] = wf[j >> 1];

    *(f16x8*)(Wblob + (size_t)blob * 16384 + (size_t)row * 128 + s * 16)
        = *(f16x8*)o;
}

// ---------- f16 MFMA GEMM over K_eff=2048, r2 drain discipline ----------
// Block 128x128, 4 waves 2x2 (wave tile 64x64), 16x16x32_f16, 32KB LDS
// single buffer.  Per kt: stage 32KB -> __syncthreads (vmcnt0 drain; no
// writes in flight afterwards) -> 2 ksteps of {8 ds_read_b128 + 16 MFMA}
// -> __syncthreads.  3-4 blocks/CU hide the drain stalls.
__global__ __launch_bounds__(256)
void bru_gemm_mfma(const char* __restrict__ Ablob, const char* __restrict__ Wblob,
                   const float* __restrict__ bz, const float* __restrict__ br,
                   const float* __restrict__ bh,
                   _Float16* __restrict__ proj,
                   int nmt, int U, int Mc)
{
    __shared__ char sm[32768];   // A 16KB | B 16KB

    const int ngrid = gridDim.x;
    const int bid   = blockIdx.x;
    int lid = bid;
    if ((ngrid & 7) == 0) lid = (bid & 7) * (ngrid >> 3) + (bid >> 3);
    const int per_gate = nmt * 8;
    const int g  = lid / per_gate;
    const int r  = lid - g * per_gate;
    const int mt = r >> 3;               // nt fastest: 8 blocks share one A panel
    const int nt = r & 7;

    const int tid    = threadIdx.x;
    const int lane   = tid & 63;
    const int w      = tid >> 6;
    const int wm     = w >> 1, wn = w & 1;   // 2x2 wave grid; wave tile 64x64
    const int lane15 = lane & 15;
    const int lgrp   = lane >> 4;
    const int r7     = lane15 & 7;

    const char* asrc = Ablob + (size_t)(mt * 32) * 16384;
    const char* bsrc = Wblob + (size_t)((g * 8 + nt) * 32) * 16384;

    const int abase = (wm * 64 + lane15) * 128;           // + f*2048
    const int bbase = 16384 + (wn * 64 + lane15) * 128;   // + j*2048

    f32x4 acc[4][4];
    #pragma unroll
    for (int i = 0; i < 4; ++i)
        #pragma unroll
        for (int j = 0; j < 4; ++j) acc[i][j] = (f32x4)0.f;

    for (int kt = 0; kt < 32; ++kt) {
        const char* at = asrc + (size_t)kt * 16384;
        const char* bt = bsrc + (size_t)kt * 16384;

        #pragma unroll
        for (int c = 0; c < 4; ++c)
            gld16(sm + c * 4096 + tid * 16, at + c * 4096 + tid * 16);
        #pragma unroll
        for (int c = 0; c < 4; ++c)
            gld16(sm + 16384 + c * 4096 + tid * 16, bt + c * 4096 + tid * 16);
        __syncthreads();   // vmcnt(0) drain + barrier: LDS write-quiet after this

        #pragma unroll
        for (int ks = 0; ks < 2; ++ks) {
            const int slot = ((ks * 4 + lgrp) ^ r7) << 4;
            f16x8 af[4], bf[4];
            #pragma unroll
            for (int f = 0; f < 4; ++f)
                af[f] = *(const f16x8*)(sm + abase + f * 2048 + slot);
            #pragma unroll
            for (int j = 0; j < 4; ++j)
                bf[j] = *(const f16x8*)(sm + bbase + j * 2048 + slot);
            __builtin_amdgcn_s_setprio(1);
            #pragma unroll
            for (int f = 0; f < 4; ++f)
                #pragma unroll
                for (int j = 0; j < 4; ++j)
                    acc[f][j] = __builtin_amdgcn_mfma_f32_16x16x32_f16(
                        af[f], bf[j], acc[f][j], 0, 0, 0);
            __builtin_amdgcn_s_setprio(0);
        }
        __syncthreads();   // readers done before next kt's staging overwrites
    }

    // epilogue: C map (verified r2-lineage): col=lane&15, row=(lane>>4)*4+reg
    const float* bias = (g == 0) ? bz : (g == 1) ? br : bh;
    const int n0 = nt * 128 + wn * 64;
    float bcol[4];
    #pragma unroll
    for (int j = 0; j < 4; ++j) bcol[j] = bias[n0 + j * 16 + lane15];

    _Float16* cbase = proj + (size_t)g * Mc * U + (size_t)n0 + lane15;
    #pragma unroll
    for (int f = 0; f < 4; ++f) {
        #pragma unroll
        for (int reg = 0; reg < 4; ++reg) {
            const int row = mt * 128 + wm * 64 + f * 16 + lgrp * 4 + reg;
            #pragma unroll
            for (int j = 0; j < 4; ++j)
                cbase[(size_t)row * U + j * 16] = (_Float16)(acc[f][j][reg] + bcol[j]);
        }
    }
}

// ---------- scan: one thread per (b,u); 8-deep rotating register prefetch ----------
#define PF 8
__global__ __launch_bounds__(256)
void bru_scan(const _Float16* __restrict__ proj,
              const float* __restrict__ mz, const float* __restrict__ mr,
              float* __restrict__ out,
              float* __restrict__ hstate,
              int B, int T, int U, int Tc, int t0, int Mc)
{
    const int idx = blockIdx.x * blockDim.x + threadIdx.x;
    const int b = idx / U;
    const int u = idx - b * U;

    float h = (t0 == 0) ? 0.f : hstate[idx];
    const float vmz = mz[u];
    const float vmr = mr[u];

    const _Float16* pz = proj + (long)b * Tc * U + u;
    const _Float16* pr = pz + (long)Mc * U;
    const _Float16* ph = pr + (long)Mc * U;
    float* po = out + ((long)b * T + t0) * U + u;

    _Float16 fz[PF], fr[PF], fh[PF];
    #pragma unroll
    for (int i = 0; i < PF; ++i) {
        const long o = (long)((i < Tc) ? i : (Tc - 1)) * U;
        fz[i] = pz[o]; fr[i] = pr[o]; fh[i] = ph[o];
    }

    for (int t = 0; t < Tc; t += PF) {
        #pragma unroll
        for (int i = 0; i < PF; ++i) {
            const float xz = (float)fz[i];
            const float xr = (float)fr[i];
            const float xh = (float)fh[i];
            {
                int tn = t + i + PF; if (tn > Tc - 1) tn = Tc - 1;
                const long o = (long)tn * U;
                fz[i] = pz[o]; fr[i] = pr[o]; fh[i] = ph[o];
            }
            const float e2r = __expf(2.f * (xr + h * vmr));
            const float rr  = 2.f - 2.f / (e2r + 1.f);             // tanh(.)+1
            const float zz  = 1.f / (1.f + __expf(-(xz + h * vmz)));
            const float e2h = __expf(2.f * (xh + rr * h));
            const float hh  = 1.f - 2.f / (e2h + 1.f);             // tanh(.)
            h = (1.f - zz) * hh + zz * h;
            if (t + i < Tc) po[(long)(t + i) * U] = h;
        }
    }
    hstate[idx] = h;
}

// ---------- launch ----------
extern "C" void kernel_launch(void* const* d_in, const int* in_sizes, int n_in,
                              void* d_out, int out_size, void* d_ws, size_t ws_size,
                              hipStream_t stream)
{
    const float* x  = (const float*)d_in[0];
    const float* wz = (const float*)d_in[1];
    const float* wr = (const float*)d_in[2];
    const float* wh = (const float*)d_in[3];
    const float* mz = (const float*)d_in[4];
    const float* mr = (const float*)d_in[5];
    const float* bz = (const float*)d_in[6];
    const float* br = (const float*)d_in[7];
    const float* bh = (const float*)d_in[8];

    const int B = 64, T = 512, D = 1024, U = 1024;

    const size_t h_bytes = (size_t)B * U * sizeof(float);
    const size_t w_bytes = (size_t)768 * 16384;   // 12.58 MB

    int Tc = T;
    while (Tc > 4) {
        const int Mc_ = B * Tc;
        const size_t a_bytes_ = (size_t)Mc_ * 4096;   // (Mc/128)*32*16KB
        const size_t p_bytes_ = 3ull * Mc_ * U * sizeof(_Float16);
        if (h_bytes + w_bytes + a_bytes_ + p_bytes_ <= ws_size) break;
        Tc >>= 1;
    }
    const int nmt = B * Tc / 128;
    const int Mc  = B * Tc;
    const size_t a_bytes = (size_t)Mc * 4096;

    float*    h_state = (float*)d_ws;
    char*     Wblob   = (char*)d_ws + h_bytes;
    char*     Ablob   = (char*)d_ws + h_bytes + w_bytes;
    _Float16* proj    = (_Float16*)((char*)d_ws + h_bytes + w_bytes + a_bytes);

    bru_conv_w<<<768 * 1024 / 256, 256, 0, stream>>>(wz, wr, wh, Wblob, D, U);

    for (int t0 = 0; t0 < T; t0 += Tc) {
        bru_conv_a<<<(Mc * 32) / 256, 256, 0, stream>>>(x, Ablob, T, D, Tc, t0, Mc);

        bru_gemm_mfma<<<3 * nmt * 8, 256, 0, stream>>>(
            Ablob, Wblob, bz, br, bh, proj, nmt, U, Mc);

        bru_scan<<<(B * U) / 256, 256, 0, stream>>>(
            proj, mz, mr, (float*)d_out, h_state, B, T, U, Tc, t0, Mc);
    }
}

// Round 14
// 581.613 us; speedup vs baseline: 1.1055x; 1.0861x over previous
//
#include <hip/hip_runtime.h>
#include <cmath>

using f16x8 = __attribute__((ext_vector_type(8))) _Float16;
using f32x4 = __attribute__((ext_vector_type(4))) float;

// ---------- helpers ----------
__device__ __forceinline__ void gld16(void* lds, const void* g) {
    __builtin_amdgcn_global_load_lds(
        (const __attribute__((address_space(1))) unsigned int*)g,
        (__attribute__((address_space(3))) unsigned int*)lds, 16, 0, 0);
}

// ========= Layouts =========
// K_eff = 2048: k_eff = 2k + s; s=0 -> f16-hi(x), s=1 -> f16-lo residual.
// W_eff[2k+s][u] = w[k][u] (duplicated) -> one f16 MFMA chain = hi*w + lo*w.
//
// A-blob: per (mt256, kt) 32KB: 256 m-rows x 128B (64 k_eff).  Row r, stored
//   16B slot sh holds k_eff octet qe = sh ^ (r&7) (pre-swizzled image).
// W-blob: per (g, nt128, kt) 16KB: 128 u-rows x 128B, same swizzle, w dup'd.
// Linear global_load_lds reproduces the swizzled image.  Fragment reads use
// the 16-row geometry (rows = lane&15 groups, slot (ks*4+lgrp)^(row&7))
// which measured ZERO SQ_LDS_BANK_CONFLICT (r13); staging fully drained
// before reads (r13 discipline).

// ---------- convert x -> A blob ----------
__global__ __launch_bounds__(256)
void bru_conv_a(const float* __restrict__ x, char* __restrict__ Ablob,
                int T, int D, int Tc, int t0, int Mc)
{
    const int gid = blockIdx.x * 256 + threadIdx.x;   // Mc*32 threads
    const int kt = gid / Mc;
    const int m  = gid - kt * Mc;
    const int mt = m >> 8, row = m & 255;

    const long xrow = (long)(m / Tc) * T + t0 + (m % Tc);
    const float* src = x + xrow * (long)D + kt * 32;

    float v[32];
    #pragma unroll
    for (int i = 0; i < 8; ++i)
        *(float4*)&v[i * 4] = *(const float4*)(src + i * 4);

    _Float16 hi[32], lo[32];
    #pragma unroll
    for (int k = 0; k < 32; ++k) {
        hi[k] = (_Float16)v[k];
        lo[k] = (_Float16)(v[k] - (float)hi[k]);
    }

    char* base = Ablob + ((size_t)(mt * 32 + kt)) * 32768 + (size_t)row * 128;
    #pragma unroll
    for (int qe = 0; qe < 8; ++qe) {
        _Float16 o[8];
        #pragma unroll
        for (int j = 0; j < 8; ++j) {
            const int k = qe * 4 + (j >> 1);
            o[j] = (j & 1) ? lo[k] : hi[k];
        }
        *(f16x8*)(base + ((qe ^ (row & 7)) << 4)) = *(f16x8*)o;
    }
}

// ---------- convert W (3 gates) -> W_eff blobs ----------
__global__ __launch_bounds__(256)
void bru_conv_w(const float* __restrict__ wz, const float* __restrict__ wr,
                const float* __restrict__ wh, char* __restrict__ Wblob,
                int D, int U)
{
    const int gid  = blockIdx.x * 256 + threadIdx.x;  // 768*1024 threads
    const int blob = gid >> 10;           // (g*8+nt)*32 + kt
    const int idx  = gid & 1023;
    const int row  = idx >> 3;            // u within 128-col tile
    const int s    = idx & 7;

    const int g    = blob >> 8;
    const int rest = blob & 255;
    const int nt   = rest >> 5;
    const int kt   = rest & 31;

    const float* W = (g == 0) ? wz : (g == 1) ? wr : wh;
    const int qe   = s ^ (row & 7);
    const int ucol = nt * 128 + row;

    _Float16 wf[4];
    #pragma unroll
    for (int jj = 0; jj < 4; ++jj)
        wf[jj] = (_Float16)W[(long)(kt * 32 + qe * 4 + jj) * U + ucol];

    _Float16 o[8];
    #pragma unroll
    for (int j = 0; j < 8; ++j) o[j] = wf[j >> 1];

    *(f16x8*)(Wblob + (size_t)blob * 16384 + (size_t)row * 128 + s * 16)
        = *(f16x8*)o;
}

// ---------- f16 MFMA GEMM over K_eff=2048 ----------
// Block 256x128, 4 waves 2x2, wave tile 128m x 64n (FLOP/LDS-byte 42.7 vs
// r13's 32), 16x16x32_f16, 48KB LDS single buffer, 2 blocks/CU.
// Per kt: stage 48KB -> __syncthreads (drain) -> 2 ksteps {12 ds_read,
// 32 MFMA} -> __syncthreads.  Conflict-free 16-row fragment geometry.
__global__ __launch_bounds__(256, 2)
void bru_gemm_mfma(const char* __restrict__ Ablob, const char* __restrict__ Wblob,
                   const float* __restrict__ bz, const float* __restrict__ br,
                   const float* __restrict__ bh,
                   _Float16* __restrict__ proj,
                   int nmt, int U, int Mc)
{
    __shared__ char sm[49152];   // A 32KB | B 16KB

    const int ngrid = gridDim.x;
    const int bid   = blockIdx.x;
    int lid = bid;
    if ((ngrid & 7) == 0) lid = (bid & 7) * (ngrid >> 3) + (bid >> 3);
    const int per_gate = nmt * 8;
    const int g  = lid / per_gate;
    const int r  = lid - g * per_gate;
    const int mt = r >> 3;               // nt fastest: 8 blocks share one A panel
    const int nt = r & 7;

    const int tid    = threadIdx.x;
    const int lane   = tid & 63;
    const int w      = tid >> 6;
    const int wm     = w >> 1, wn = w & 1;   // 2x2 wave grid; wave tile 128x64
    const int lane15 = lane & 15;
    const int lgrp   = lane >> 4;
    const int r7     = lane15 & 7;

    // hoisted, incremented pointers (kills per-kt address VALU)
    const char* a_ptr = Ablob + (size_t)(mt * 32) * 32768 + tid * 16;
    const char* b_ptr = Wblob + (size_t)((g * 8 + nt) * 32) * 16384 + tid * 16;

    const int abase = (wm * 128 + lane15) * 128;          // + f*2048
    const int bbase = 32768 + (wn * 64 + lane15) * 128;   // + j*2048
    const int slot0 = ((lgrp    ) ^ r7) << 4;             // ks=0
    const int slot1 = ((lgrp + 4) ^ r7) << 4;             // ks=1

    f32x4 acc[8][4];
    #pragma unroll
    for (int i = 0; i < 8; ++i)
        #pragma unroll
        for (int j = 0; j < 4; ++j) acc[i][j] = (f32x4)0.f;

    for (int kt = 0; kt < 32; ++kt) {
        #pragma unroll
        for (int c = 0; c < 8; ++c)
            gld16(sm + c * 4096 + tid * 16, a_ptr + c * 4096);
        #pragma unroll
        for (int c = 0; c < 4; ++c)
            gld16(sm + 32768 + c * 4096 + tid * 16, b_ptr + c * 4096);
        a_ptr += 32768;
        b_ptr += 16384;
        __syncthreads();   // vmcnt(0) drain + barrier: LDS write-quiet after

        #pragma unroll
        for (int ks = 0; ks < 2; ++ks) {
            const int slot = ks ? slot1 : slot0;
            f16x8 af[8], bf[4];
            #pragma unroll
            for (int f = 0; f < 8; ++f)
                af[f] = *(const f16x8*)(sm + abase + f * 2048 + slot);
            #pragma unroll
            for (int j = 0; j < 4; ++j)
                bf[j] = *(const f16x8*)(sm + bbase + j * 2048 + slot);
            __builtin_amdgcn_s_setprio(1);
            #pragma unroll
            for (int f = 0; f < 8; ++f)
                #pragma unroll
                for (int j = 0; j < 4; ++j)
                    acc[f][j] = __builtin_amdgcn_mfma_f32_16x16x32_f16(
                        af[f], bf[j], acc[f][j], 0, 0, 0);
            __builtin_amdgcn_s_setprio(0);
        }
        __syncthreads();   // readers done before next kt's staging overwrites
    }

    // epilogue: C map (r13-verified): col=lane&15, row=lgrp*4+reg
    const float* bias = (g == 0) ? bz : (g == 1) ? br : bh;
    const int n0 = nt * 128 + wn * 64;
    float bcol[4];
    #pragma unroll
    for (int j = 0; j < 4; ++j) bcol[j] = bias[n0 + j * 16 + lane15];

    _Float16* cbase = proj + (size_t)g * Mc * U + (size_t)n0 + lane15;
    #pragma unroll
    for (int f = 0; f < 8; ++f) {
        #pragma unroll
        for (int reg = 0; reg < 4; ++reg) {
            const int row = mt * 256 + wm * 128 + f * 16 + lgrp * 4 + reg;
            #pragma unroll
            for (int j = 0; j < 4; ++j)
                cbase[(size_t)row * U + j * 16] = (_Float16)(acc[f][j][reg] + bcol[j]);
        }
    }
}

// ---------- scan: one thread per (b,u); 8-deep rotating register prefetch ----------
#define PF 8
__global__ __launch_bounds__(256)
void bru_scan(const _Float16* __restrict__ proj,
              const float* __restrict__ mz, const float* __restrict__ mr,
              float* __restrict__ out,
              float* __restrict__ hstate,
              int B, int T, int U, int Tc, int t0, int Mc)
{
    const int idx = blockIdx.x * blockDim.x + threadIdx.x;
    const int b = idx / U;
    const int u = idx - b * U;

    float h = (t0 == 0) ? 0.f : hstate[idx];
    const float vmz = mz[u];
    const float vmr = mr[u];

    const _Float16* pz = proj + (long)b * Tc * U + u;
    const _Float16* pr = pz + (long)Mc * U;
    const _Float16* ph = pr + (long)Mc * U;
    float* po = out + ((long)b * T + t0) * U + u;

    _Float16 fz[PF], fr[PF], fh[PF];
    #pragma unroll
    for (int i = 0; i < PF; ++i) {
        const long o = (long)((i < Tc) ? i : (Tc - 1)) * U;
        fz[i] = pz[o]; fr[i] = pr[o]; fh[i] = ph[o];
    }

    for (int t = 0; t < Tc; t += PF) {
        #pragma unroll
        for (int i = 0; i < PF; ++i) {
            const float xz = (float)fz[i];
            const float xr = (float)fr[i];
            const float xh = (float)fh[i];
            {
                int tn = t + i + PF; if (tn > Tc - 1) tn = Tc - 1;
                const long o = (long)tn * U;
                fz[i] = pz[o]; fr[i] = pr[o]; fh[i] = ph[o];
            }
            const float e2r = __expf(2.f * (xr + h * vmr));
            const float rr  = 2.f - 2.f / (e2r + 1.f);             // tanh(.)+1
            const float zz  = 1.f / (1.f + __expf(-(xz + h * vmz)));
            const float e2h = __expf(2.f * (xh + rr * h));
            const float hh  = 1.f - 2.f / (e2h + 1.f);             // tanh(.)
            h = (1.f - zz) * hh + zz * h;
            if (t + i < Tc) po[(long)(t + i) * U] = h;
        }
    }
    hstate[idx] = h;
}

// ---------- launch ----------
extern "C" void kernel_launch(void* const* d_in, const int* in_sizes, int n_in,
                              void* d_out, int out_size, void* d_ws, size_t ws_size,
                              hipStream_t stream)
{
    const float* x  = (const float*)d_in[0];
    const float* wz = (const float*)d_in[1];
    const float* wr = (const float*)d_in[2];
    const float* wh = (const float*)d_in[3];
    const float* mz = (const float*)d_in[4];
    const float* mr = (const float*)d_in[5];
    const float* bz = (const float*)d_in[6];
    const float* br = (const float*)d_in[7];
    const float* bh = (const float*)d_in[8];

    const int B = 64, T = 512, D = 1024, U = 1024;

    const size_t h_bytes = (size_t)B * U * sizeof(float);
    const size_t w_bytes = (size_t)768 * 16384;   // 12.58 MB

    int Tc = T;
    while (Tc > 4) {
        const int Mc_ = B * Tc;
        const size_t a_bytes_ = (size_t)Mc_ * 4096;   // (Mc/256)*32*32KB
        const size_t p_bytes_ = 3ull * Mc_ * U * sizeof(_Float16);
        if (h_bytes + w_bytes + a_bytes_ + p_bytes_ <= ws_size) break;
        Tc >>= 1;
    }
    const int nmt = B * Tc / 256;
    const int Mc  = B * Tc;
    const size_t a_bytes = (size_t)Mc * 4096;

    float*    h_state = (float*)d_ws;
    char*     Wblob   = (char*)d_ws + h_bytes;
    char*     Ablob   = (char*)d_ws + h_bytes + w_bytes;
    _Float16* proj    = (_Float16*)((char*)d_ws + h_bytes + w_bytes + a_bytes);

    bru_conv_w<<<768 * 1024 / 256, 256, 0, stream>>>(wz, wr, wh, Wblob, D, U);

    for (int t0 = 0; t0 < T; t0 += Tc) {
        bru_conv_a<<<(Mc * 32) / 256, 256, 0, stream>>>(x, Ablob, T, D, Tc, t0, Mc);

        bru_gemm_mfma<<<3 * nmt * 8, 256, 0, stream>>>(
            Ablob, Wblob, bz, br, bh, proj, nmt, U, Mc);

        bru_scan<<<(B * U) / 256, 256, 0, stream>>>(
            proj, mz, mr, (float*)d_out, h_state, B, T, U, Tc, t0, Mc);
    }
}

// Round 15
// 554.769 us; speedup vs baseline: 1.1590x; 1.0484x over previous
//
#include <hip/hip_runtime.h>
#include <cmath>

using f16x8 = __attribute__((ext_vector_type(8))) _Float16;
using f32x4 = __attribute__((ext_vector_type(4))) float;

// ---------- helpers ----------
__device__ __forceinline__ void gld16(void* lds, const void* g) {
    __builtin_amdgcn_global_load_lds(
        (const __attribute__((address_space(1))) unsigned int*)g,
        (__attribute__((address_space(3))) unsigned int*)lds, 16, 0, 0);
}

// ========= Layouts =========
// f16 2-product split: x = hi + lo (f16);  proj = hi*w + lo*w, W single f16.
//
// A-blob: per (mt256, kt) 32KB: 256 m-rows x 128B = 32 real k, hi/lo planes.
//   Slot s = isLo*4 + q (q = real-k octet 0..3); stored at sh = s ^ (r&7)
//   (proven 0-conflict swizzle).  kt stride padded to 34 (distance-2 stage).
// W-blob: per (g, nt256, kt) 16KB: 256 u-rows x 64B = 32 real k, single f16.
//   Slot q stored at sh = q ^ ((r>>1)&3)  (4-slot variant: banks distinct
//   across each 8-row group).  kt stride padded to 34.
// Linear global_load_lds reproduces the swizzled images.

// ---------- convert x -> A blob ----------
__global__ __launch_bounds__(256)
void bru_conv_a(const float* __restrict__ x, char* __restrict__ Ablob,
                int T, int D, int Tc, int t0, int Mc)
{
    const int gid = blockIdx.x * 256 + threadIdx.x;   // Mc*32 threads
    const int kt = gid / Mc;
    const int m  = gid - kt * Mc;
    const int mt = m >> 8, row = m & 255;

    const long xrow = (long)(m / Tc) * T + t0 + (m % Tc);
    const float* src = x + xrow * (long)D + kt * 32;

    float v[32];
    #pragma unroll
    for (int i = 0; i < 8; ++i)
        *(float4*)&v[i * 4] = *(const float4*)(src + i * 4);

    _Float16 hi[32], lo[32];
    #pragma unroll
    for (int k = 0; k < 32; ++k) {
        hi[k] = (_Float16)v[k];
        lo[k] = (_Float16)(v[k] - (float)hi[k]);
    }

    char* base = Ablob + ((size_t)(mt * 34 + kt)) * 32768 + (size_t)row * 128;
    #pragma unroll
    for (int q = 0; q < 4; ++q) {
        _Float16 oh[8], ol[8];
        #pragma unroll
        for (int j = 0; j < 8; ++j) { oh[j] = hi[q * 8 + j]; ol[j] = lo[q * 8 + j]; }
        *(f16x8*)(base + (((q    ) ^ (row & 7)) << 4)) = *(f16x8*)oh;
        *(f16x8*)(base + (((q + 4) ^ (row & 7)) << 4)) = *(f16x8*)ol;
    }
}

// ---------- convert W (3 gates) -> W blobs (single f16) ----------
__global__ __launch_bounds__(256)
void bru_conv_w(const float* __restrict__ wz, const float* __restrict__ wr,
                const float* __restrict__ wh, char* __restrict__ Wblob,
                int D, int U)
{
    const int gid  = blockIdx.x * 256 + threadIdx.x;  // 12*32*256 threads
    const int blob = gid >> 8;            // (g*4+nt)*32 + kt
    const int row  = gid & 255;           // u within 256-col tile (coalesced)

    const int g    = blob >> 7;
    const int rest = blob & 127;
    const int nt   = rest >> 5;
    const int kt   = rest & 31;

    const float* W = (g == 0) ? wz : (g == 1) ? wr : wh;
    const int ucol = nt * 256 + row;

    char* base = Wblob + ((size_t)((g * 4 + nt) * 34 + kt)) * 16384 + (size_t)row * 64;
    #pragma unroll
    for (int q = 0; q < 4; ++q) {
        _Float16 o[8];
        #pragma unroll
        for (int j = 0; j < 8; ++j)
            o[j] = (_Float16)W[(long)(kt * 32 + q * 8 + j) * U + ucol];
        *(f16x8*)(base + ((q ^ ((row >> 1) & 3)) << 4)) = *(f16x8*)o;
    }
}

// ---------- f16 2-product MFMA GEMM, distance-2 counted-vmcnt pipeline ----------
// Block 256x256, 8 waves 2x4 (wave tile 128m x 64n), 16x16x32_f16.
// A: 3 x 32KB buffers; B: 3 x 16KB buffers (144KB LDS, 1 block/CU, 2 waves/SIMD).
// Per kt: stage(kt+2) issue -> 20 ds_read -> lgkmcnt(0) -> 64 MFMA ->
// vmcnt(6) (drains stage issued a full iteration earlier, ~free) -> s_barrier.
__global__ __launch_bounds__(512, 2)
void bru_gemm_mfma(const char* __restrict__ Ablob, const char* __restrict__ Wblob,
                   const float* __restrict__ bz, const float* __restrict__ br,
                   const float* __restrict__ bh,
                   _Float16* __restrict__ proj,
                   int nmt, int U, int Mc)
{
    __shared__ char sm[147456];   // A: 3x32KB @0 | B: 3x16KB @98304

    const int ngrid = gridDim.x;
    const int bid   = blockIdx.x;
    int lid = bid;
    if ((ngrid & 7) == 0) lid = (bid & 7) * (ngrid >> 3) + (bid >> 3);
    const int mt  = lid / 12;
    const int rem = lid - mt * 12;
    const int g   = rem >> 2;
    const int nt  = rem & 3;

    const int tid  = threadIdx.x;
    const int lane = tid & 63;
    const int w    = tid >> 6;
    const int wm   = w >> 2, wn = w & 3;   // 2x4 wave grid; wave tile 128x64
    const int l15  = lane & 15;
    const int lgrp = lane >> 4;

    const char* asrc = Ablob + (size_t)(mt * 34) * 32768;
    const char* bsrc = Wblob + (size_t)((g * 4 + nt) * 34) * 16384;
    const int st = tid * 16;

    const int abase = (wm * 128 + l15) * 128;          // + f*2048
    const int slotA = (lgrp ^ (l15 & 7)) << 4;         // lo at ^64
    const int bbase = 98304 + (wn * 64 + l15) * 64;    // + j*1024
    const int slotB = (lgrp ^ ((l15 >> 1) & 3)) << 4;

    f32x4 acc[8][4];
    #pragma unroll
    for (int i = 0; i < 8; ++i)
        #pragma unroll
        for (int j = 0; j < 4; ++j) acc[i][j] = (f32x4)0.f;

#define STAGE(kt_) do { \
    const int bb_ = (kt_) % 3; \
    _Pragma("unroll") for (int c_ = 0; c_ < 4; ++c_) \
        gld16(sm + bb_ * 32768 + c_ * 8192 + st, \
              asrc + (size_t)(kt_) * 32768 + c_ * 8192 + st); \
    _Pragma("unroll") for (int c_ = 0; c_ < 2; ++c_) \
        gld16(sm + 98304 + bb_ * 16384 + c_ * 8192 + st, \
              bsrc + (size_t)(kt_) * 16384 + c_ * 8192 + st); } while (0)

    // prologue: stage kt 0,1; wait for kt0 (leave kt1's 6 in flight)
    STAGE(0); STAGE(1);
    __builtin_amdgcn_sched_barrier(0);
    asm volatile("s_waitcnt vmcnt(6)" ::: "memory");
    __builtin_amdgcn_sched_barrier(0);
    __builtin_amdgcn_s_barrier();

    for (int kt = 0; kt < 32; ++kt) {
        const int cb = kt % 3;

        STAGE(kt + 2);   // pads kt 32,33 exist; staged but never read

        const char* sa = sm + cb * 32768;
        const char* sb = sm + cb * 16384;   // + 98304 in bbase
        f16x8 ah[8], al[8], bf[4];
        #pragma unroll
        for (int f = 0; f < 8; ++f) {
            ah[f] = *(const f16x8*)(sa + abase + f * 2048 + slotA);
            al[f] = *(const f16x8*)(sa + abase + f * 2048 + (slotA ^ 64));
        }
        #pragma unroll
        for (int j = 0; j < 4; ++j)
            bf[j] = *(const f16x8*)(sb + bbase + j * 1024 + slotB);

        asm volatile("s_waitcnt lgkmcnt(0)" ::: "memory");
        __builtin_amdgcn_sched_barrier(0);
        __builtin_amdgcn_s_setprio(1);
        #pragma unroll
        for (int f = 0; f < 8; ++f)
            #pragma unroll
            for (int j = 0; j < 4; ++j) {
                acc[f][j] = __builtin_amdgcn_mfma_f32_16x16x32_f16(ah[f], bf[j], acc[f][j], 0, 0, 0);
                acc[f][j] = __builtin_amdgcn_mfma_f32_16x16x32_f16(al[f], bf[j], acc[f][j], 0, 0, 0);
            }
        __builtin_amdgcn_s_setprio(0);

        // counted fence: leave only this kt's 6 stages outstanding ->
        // stage(kt+1) (issued last iteration) is complete before next reads.
        __builtin_amdgcn_sched_barrier(0);
        asm volatile("s_waitcnt vmcnt(6)" ::: "memory");
        __builtin_amdgcn_sched_barrier(0);
        __builtin_amdgcn_s_barrier();
    }
#undef STAGE

    // epilogue: C map (proven): col=lane&15, row=lgrp*4+reg
    const float* bias = (g == 0) ? bz : (g == 1) ? br : bh;
    const int n0 = nt * 256 + wn * 64;
    float bcol[4];
    #pragma unroll
    for (int j = 0; j < 4; ++j) bcol[j] = bias[n0 + j * 16 + l15];

    _Float16* cbase = proj + (size_t)g * Mc * U + (size_t)n0 + l15;
    #pragma unroll
    for (int f = 0; f < 8; ++f) {
        #pragma unroll
        for (int reg = 0; reg < 4; ++reg) {
            const int row = mt * 256 + wm * 128 + f * 16 + lgrp * 4 + reg;
            #pragma unroll
            for (int j = 0; j < 4; ++j)
                cbase[(size_t)row * U + j * 16] = (_Float16)(acc[f][j][reg] + bcol[j]);
        }
    }
}

// ---------- scan: one thread per (b,u); 8-deep rotating register prefetch ----------
#define PF 8
__global__ __launch_bounds__(256)
void bru_scan(const _Float16* __restrict__ proj,
              const float* __restrict__ mz, const float* __restrict__ mr,
              float* __restrict__ out,
              float* __restrict__ hstate,
              int B, int T, int U, int Tc, int t0, int Mc)
{
    const int idx = blockIdx.x * blockDim.x + threadIdx.x;
    const int b = idx / U;
    const int u = idx - b * U;

    float h = (t0 == 0) ? 0.f : hstate[idx];
    const float vmz = mz[u];
    const float vmr = mr[u];

    const _Float16* pz = proj + (long)b * Tc * U + u;
    const _Float16* pr = pz + (long)Mc * U;
    const _Float16* ph = pr + (long)Mc * U;
    float* po = out + ((long)b * T + t0) * U + u;

    _Float16 fz[PF], fr[PF], fh[PF];
    #pragma unroll
    for (int i = 0; i < PF; ++i) {
        const long o = (long)((i < Tc) ? i : (Tc - 1)) * U;
        fz[i] = pz[o]; fr[i] = pr[o]; fh[i] = ph[o];
    }

    for (int t = 0; t < Tc; t += PF) {
        #pragma unroll
        for (int i = 0; i < PF; ++i) {
            const float xz = (float)fz[i];
            const float xr = (float)fr[i];
            const float xh = (float)fh[i];
            {
                int tn = t + i + PF; if (tn > Tc - 1) tn = Tc - 1;
                const long o = (long)tn * U;
                fz[i] = pz[o]; fr[i] = pr[o]; fh[i] = ph[o];
            }
            const float e2r = __expf(2.f * (xr + h * vmr));
            const float rr  = 2.f - 2.f / (e2r + 1.f);             // tanh(.)+1
            const float zz  = 1.f / (1.f + __expf(-(xz + h * vmz)));
            const float e2h = __expf(2.f * (xh + rr * h));
            const float hh  = 1.f - 2.f / (e2h + 1.f);             // tanh(.)
            h = (1.f - zz) * hh + zz * h;
            if (t + i < Tc) po[(long)(t + i) * U] = h;
        }
    }
    hstate[idx] = h;
}

// ---------- launch ----------
extern "C" void kernel_launch(void* const* d_in, const int* in_sizes, int n_in,
                              void* d_out, int out_size, void* d_ws, size_t ws_size,
                              hipStream_t stream)
{
    const float* x  = (const float*)d_in[0];
    const float* wz = (const float*)d_in[1];
    const float* wr = (const float*)d_in[2];
    const float* wh = (const float*)d_in[3];
    const float* mz = (const float*)d_in[4];
    const float* mr = (const float*)d_in[5];
    const float* bz = (const float*)d_in[6];
    const float* br = (const float*)d_in[7];
    const float* bh = (const float*)d_in[8];

    const int B = 64, T = 512, D = 1024, U = 1024;

    const size_t h_bytes = (size_t)B * U * sizeof(float);
    const size_t w_bytes = (size_t)12 * 34 * 16384;   // 6.68 MB incl. pad

    int Tc = T;
    while (Tc > 4) {
        const int nmt_ = B * Tc / 256;
        const size_t a_bytes_ = (size_t)nmt_ * 34 * 32768;
        const size_t p_bytes_ = 3ull * B * Tc * U * sizeof(_Float16);
        if (h_bytes + w_bytes + a_bytes_ + p_bytes_ <= ws_size) break;
        Tc >>= 1;
    }
    const int nmt = B * Tc / 256;
    const int Mc  = B * Tc;
    const size_t a_bytes = (size_t)nmt * 34 * 32768;

    float*    h_state = (float*)d_ws;
    char*     Wblob   = (char*)d_ws + h_bytes;
    char*     Ablob   = (char*)d_ws + h_bytes + w_bytes;
    _Float16* proj    = (_Float16*)((char*)d_ws + h_bytes + w_bytes + a_bytes);

    bru_conv_w<<<12 * 32 * 256 / 256, 256, 0, stream>>>(wz, wr, wh, Wblob, D, U);

    for (int t0 = 0; t0 < T; t0 += Tc) {
        bru_conv_a<<<(Mc * 32) / 256, 256, 0, stream>>>(x, Ablob, T, D, Tc, t0, Mc);

        bru_gemm_mfma<<<3 * nmt * 4, 512, 0, stream>>>(
            Ablob, Wblob, bz, br, bh, proj, nmt, U, Mc);

        bru_scan<<<(B * U) / 256, 256, 0, stream>>>(
            proj, mz, mr, (float*)d_out, h_state, B, T, U, Tc, t0, Mc);
    }
}

// Round 16
// 553.287 us; speedup vs baseline: 1.1621x; 1.0027x over previous
//
#include <hip/hip_runtime.h>
#include <cmath>

using f16x8 = __attribute__((ext_vector_type(8))) _Float16;
using f32x4 = __attribute__((ext_vector_type(4))) float;

// ---------- helpers ----------
__device__ __forceinline__ void gld16(void* lds, const void* g) {
    __builtin_amdgcn_global_load_lds(
        (const __attribute__((address_space(1))) unsigned int*)g,
        (__attribute__((address_space(3))) unsigned int*)lds, 16, 0, 0);
}

// ========= Layouts =========
// f16 2-product split: x = hi + lo (f16);  proj = hi*w + lo*w, W single f16.
//
// A-blob: per (mt256, kt) 32KB: 256 m-rows x 128B = 32 real k, hi/lo planes.
//   Slot s = isLo*4 + q (q = real-k octet 0..3); stored at sh = s ^ (r&7)
//   (proven 0-conflict swizzle).  kt stride padded to 34 (distance-2 stage).
// W-blob: per (g, nt256, kt) 16KB: 256 u-rows x 64B = 32 real k, single f16.
//   Slot q stored at sh = q ^ ((r>>1)&3).  kt stride padded to 34.
// Linear global_load_lds reproduces the swizzled images.

// ---------- convert x -> A blob ----------
__global__ __launch_bounds__(256)
void bru_conv_a(const float* __restrict__ x, char* __restrict__ Ablob,
                int T, int D, int Tc, int t0, int Mc)
{
    const int gid = blockIdx.x * 256 + threadIdx.x;   // Mc*32 threads
    const int kt = gid / Mc;
    const int m  = gid - kt * Mc;
    const int mt = m >> 8, row = m & 255;

    const long xrow = (long)(m / Tc) * T + t0 + (m % Tc);
    const float* src = x + xrow * (long)D + kt * 32;

    float v[32];
    #pragma unroll
    for (int i = 0; i < 8; ++i)
        *(float4*)&v[i * 4] = *(const float4*)(src + i * 4);

    _Float16 hi[32], lo[32];
    #pragma unroll
    for (int k = 0; k < 32; ++k) {
        hi[k] = (_Float16)v[k];
        lo[k] = (_Float16)(v[k] - (float)hi[k]);
    }

    char* base = Ablob + ((size_t)(mt * 34 + kt)) * 32768 + (size_t)row * 128;
    #pragma unroll
    for (int q = 0; q < 4; ++q) {
        _Float16 oh[8], ol[8];
        #pragma unroll
        for (int j = 0; j < 8; ++j) { oh[j] = hi[q * 8 + j]; ol[j] = lo[q * 8 + j]; }
        *(f16x8*)(base + (((q    ) ^ (row & 7)) << 4)) = *(f16x8*)oh;
        *(f16x8*)(base + (((q + 4) ^ (row & 7)) << 4)) = *(f16x8*)ol;
    }
}

// ---------- convert W (3 gates) -> W blobs (single f16) ----------
__global__ __launch_bounds__(256)
void bru_conv_w(const float* __restrict__ wz, const float* __restrict__ wr,
                const float* __restrict__ wh, char* __restrict__ Wblob,
                int D, int U)
{
    const int gid  = blockIdx.x * 256 + threadIdx.x;  // 12*32*256 threads
    const int blob = gid >> 8;            // (g*4+nt)*32 + kt
    const int row  = gid & 255;           // u within 256-col tile (coalesced)

    const int g    = blob >> 7;
    const int rest = blob & 127;
    const int nt   = rest >> 5;
    const int kt   = rest & 31;

    const float* W = (g == 0) ? wz : (g == 1) ? wr : wh;
    const int ucol = nt * 256 + row;

    char* base = Wblob + ((size_t)((g * 4 + nt) * 34 + kt)) * 16384 + (size_t)row * 64;
    #pragma unroll
    for (int q = 0; q < 4; ++q) {
        _Float16 o[8];
        #pragma unroll
        for (int j = 0; j < 8; ++j)
            o[j] = (_Float16)W[(long)(kt * 32 + q * 8 + j) * U + ucol];
        *(f16x8*)(base + ((q ^ ((row >> 1) & 3)) << 4)) = *(f16x8*)o;
    }
}

// ---------- f16 2-product MFMA GEMM, 4-phase interleave + counted vmcnt ----------
// Block 256x256, 8 waves 2x4 (wave tile 128m x 64n), 16x16x32_f16.
// A: 3 x 32KB; B: 3 x 16KB (144KB LDS).  Per kt: 4 phases, each
// {4-6 ds_read ∥ 2 gld16(kt+2) ∥ barrier ∥ lgkmcnt(0) ∥ setprio(1) 16 MFMA
// setprio(0) ∥ barrier}; vmcnt(6) once per kt (phase 3), never 0.
__global__ __launch_bounds__(512, 2)
void bru_gemm_mfma(const char* __restrict__ Ablob, const char* __restrict__ Wblob,
                   const float* __restrict__ bz, const float* __restrict__ br,
                   const float* __restrict__ bh,
                   _Float16* __restrict__ proj,
                   int nmt, int U, int Mc)
{
    __shared__ char sm[147456];   // A: 3x32KB @0 | B: 3x16KB @98304

    const int ngrid = gridDim.x;
    const int bid   = blockIdx.x;
    int lid = bid;
    if ((ngrid & 7) == 0) lid = (bid & 7) * (ngrid >> 3) + (bid >> 3);
    const int mt  = lid / 12;
    const int rem = lid - mt * 12;
    const int g   = rem >> 2;
    const int nt  = rem & 3;

    const int tid  = threadIdx.x;
    const int lane = tid & 63;
    const int w    = tid >> 6;
    const int wm   = w >> 2, wn = w & 3;   // 2x4 wave grid; wave tile 128x64
    const int l15  = lane & 15;
    const int lgrp = lane >> 4;

    const char* asrc = Ablob + (size_t)(mt * 34) * 32768;
    const char* bsrc = Wblob + (size_t)((g * 4 + nt) * 34) * 16384;
    const int st = tid * 16;

    const int abase = (wm * 128 + l15) * 128;          // + f*2048
    const int slotA = (lgrp ^ (l15 & 7)) << 4;         // lo at ^64
    const int bbase = (wn * 64 + l15) * 64;            // + j*1024
    const int slotB = (lgrp ^ ((l15 >> 1) & 3)) << 4;

    f32x4 acc[8][4];
    #pragma unroll
    for (int i = 0; i < 8; ++i)
        #pragma unroll
        for (int j = 0; j < 4; ++j) acc[i][j] = (f32x4)0.f;

#define STAGE(kt_) do { \
    const int bb_ = (kt_) % 3; \
    _Pragma("unroll") for (int c_ = 0; c_ < 4; ++c_) \
        gld16(sm + bb_ * 32768 + c_ * 8192 + st, \
              asrc + (size_t)(kt_) * 32768 + c_ * 8192 + st); \
    _Pragma("unroll") for (int c_ = 0; c_ < 2; ++c_) \
        gld16(sm + 98304 + bb_ * 16384 + c_ * 8192 + st, \
              bsrc + (size_t)(kt_) * 16384 + c_ * 8192 + st); } while (0)

    // prologue: stage kt 0,1; wait kt0 complete (leave kt1's 6 in flight)
    STAGE(0); STAGE(1);
    __builtin_amdgcn_sched_barrier(0);
    asm volatile("s_waitcnt vmcnt(6)" ::: "memory");
    __builtin_amdgcn_sched_barrier(0);
    __builtin_amdgcn_s_barrier();

    for (int kt = 0; kt < 32; ++kt) {
        const int cb = kt % 3;
        const int sn = (kt + 2) % 3;
        const char* sa = sm + cb * 32768;
        const char* sb = sm + 98304 + cb * 16384;
        char* na = sm + sn * 32768;
        char* nb = sm + 98304 + sn * 16384;
        const char* ga = asrc + (size_t)(kt + 2) * 32768;   // pads 32,33 exist
        const char* gb = bsrc + (size_t)(kt + 2) * 16384;

        f16x8 bf[4];
        #pragma unroll
        for (int p = 0; p < 4; ++p) {
            // phase reads: A m-chunk {2p, 2p+1}, hi+lo
            f16x8 ah0 = *(const f16x8*)(sa + abase + (2*p    ) * 2048 + slotA);
            f16x8 al0 = *(const f16x8*)(sa + abase + (2*p    ) * 2048 + (slotA ^ 64));
            f16x8 ah1 = *(const f16x8*)(sa + abase + (2*p + 1) * 2048 + slotA);
            f16x8 al1 = *(const f16x8*)(sa + abase + (2*p + 1) * 2048 + (slotA ^ 64));
            if (p == 0) {
                #pragma unroll
                for (int j = 0; j < 4; ++j)
                    bf[j] = *(const f16x8*)(sb + bbase + j * 1024 + slotB);
            }
            // stage spread: 2 gld16/phase (phases 0-2), kt+2
            if (p == 0) {
                gld16(na + st,        ga + st);
                gld16(na + 8192 + st, ga + 8192 + st);
            } else if (p == 1) {
                gld16(na + 16384 + st, ga + 16384 + st);
                gld16(na + 24576 + st, ga + 24576 + st);
            } else if (p == 2) {
                gld16(nb + st,        gb + st);
                gld16(nb + 8192 + st, gb + 8192 + st);
            }
            __builtin_amdgcn_s_barrier();
            asm volatile("s_waitcnt lgkmcnt(0)" ::: "memory");
            __builtin_amdgcn_sched_barrier(0);
            __builtin_amdgcn_s_setprio(1);
            #pragma unroll
            for (int j = 0; j < 4; ++j) {
                acc[2*p    ][j] = __builtin_amdgcn_mfma_f32_16x16x32_f16(ah0, bf[j], acc[2*p    ][j], 0, 0, 0);
                acc[2*p    ][j] = __builtin_amdgcn_mfma_f32_16x16x32_f16(al0, bf[j], acc[2*p    ][j], 0, 0, 0);
                acc[2*p + 1][j] = __builtin_amdgcn_mfma_f32_16x16x32_f16(ah1, bf[j], acc[2*p + 1][j], 0, 0, 0);
                acc[2*p + 1][j] = __builtin_amdgcn_mfma_f32_16x16x32_f16(al1, bf[j], acc[2*p + 1][j], 0, 0, 0);
            }
            __builtin_amdgcn_s_setprio(0);
            if (p == 3) {
                // counted fence once per kt: leave this kt's 6 stages
                // outstanding -> stage(kt+1) (issued last kt) complete.
                __builtin_amdgcn_sched_barrier(0);
                asm volatile("s_waitcnt vmcnt(6)" ::: "memory");
                __builtin_amdgcn_sched_barrier(0);
            }
            __builtin_amdgcn_s_barrier();
        }
    }
#undef STAGE

    // epilogue: C map (proven): col=lane&15, row=lgrp*4+reg
    const float* bias = (g == 0) ? bz : (g == 1) ? br : bh;
    const int n0 = nt * 256 + wn * 64;
    float bcol[4];
    #pragma unroll
    for (int j = 0; j < 4; ++j) bcol[j] = bias[n0 + j * 16 + l15];

    _Float16* cbase = proj + (size_t)g * Mc * U + (size_t)n0 + l15;
    #pragma unroll
    for (int f = 0; f < 8; ++f) {
        #pragma unroll
        for (int reg = 0; reg < 4; ++reg) {
            const int row = mt * 256 + wm * 128 + f * 16 + lgrp * 4 + reg;
            #pragma unroll
            for (int j = 0; j < 4; ++j)
                cbase[(size_t)row * U + j * 16] = (_Float16)(acc[f][j][reg] + bcol[j]);
        }
    }
}

// ---------- scan: one thread per (b,u); 8-deep rotating register prefetch ----------
#define PF 8
__global__ __launch_bounds__(256)
void bru_scan(const _Float16* __restrict__ proj,
              const float* __restrict__ mz, const float* __restrict__ mr,
              float* __restrict__ out,
              float* __restrict__ hstate,
              int B, int T, int U, int Tc, int t0, int Mc)
{
    const int idx = blockIdx.x * blockDim.x + threadIdx.x;
    const int b = idx / U;
    const int u = idx - b * U;

    float h = (t0 == 0) ? 0.f : hstate[idx];
    const float vmz = mz[u];
    const float vmr = mr[u];

    const _Float16* pz = proj + (long)b * Tc * U + u;
    const _Float16* pr = pz + (long)Mc * U;
    const _Float16* ph = pr + (long)Mc * U;
    float* po = out + ((long)b * T + t0) * U + u;

    _Float16 fz[PF], fr[PF], fh[PF];
    #pragma unroll
    for (int i = 0; i < PF; ++i) {
        const long o = (long)((i < Tc) ? i : (Tc - 1)) * U;
        fz[i] = pz[o]; fr[i] = pr[o]; fh[i] = ph[o];
    }

    for (int t = 0; t < Tc; t += PF) {
        #pragma unroll
        for (int i = 0; i < PF; ++i) {
            const float xz = (float)fz[i];
            const float xr = (float)fr[i];
            const float xh = (float)fh[i];
            {
                int tn = t + i + PF; if (tn > Tc - 1) tn = Tc - 1;
                const long o = (long)tn * U;
                fz[i] = pz[o]; fr[i] = pr[o]; fh[i] = ph[o];
            }
            const float e2r = __expf(2.f * (xr + h * vmr));
            const float rr  = 2.f - 2.f / (e2r + 1.f);             // tanh(.)+1
            const float zz  = 1.f / (1.f + __expf(-(xz + h * vmz)));
            const float e2h = __expf(2.f * (xh + rr * h));
            const float hh  = 1.f - 2.f / (e2h + 1.f);             // tanh(.)
            h = (1.f - zz) * hh + zz * h;
            if (t + i < Tc) po[(long)(t + i) * U] = h;
        }
    }
    hstate[idx] = h;
}

// ---------- launch ----------
extern "C" void kernel_launch(void* const* d_in, const int* in_sizes, int n_in,
                              void* d_out, int out_size, void* d_ws, size_t ws_size,
                              hipStream_t stream)
{
    const float* x  = (const float*)d_in[0];
    const float* wz = (const float*)d_in[1];
    const float* wr = (const float*)d_in[2];
    const float* wh = (const float*)d_in[3];
    const float* mz = (const float*)d_in[4];
    const float* mr = (const float*)d_in[5];
    const float* bz = (const float*)d_in[6];
    const float* br = (const float*)d_in[7];
    const float* bh = (const float*)d_in[8];

    const int B = 64, T = 512, D = 1024, U = 1024;

    const size_t h_bytes = (size_t)B * U * sizeof(float);
    const size_t w_bytes = (size_t)12 * 34 * 16384;   // 6.68 MB incl. pad

    int Tc = T;
    while (Tc > 4) {
        const int nmt_ = B * Tc / 256;
        const size_t a_bytes_ = (size_t)nmt_ * 34 * 32768;
        const size_t p_bytes_ = 3ull * B * Tc * U * sizeof(_Float16);
        if (h_bytes + w_bytes + a_bytes_ + p_bytes_ <= ws_size) break;
        Tc >>= 1;
    }
    const int nmt = B * Tc / 256;
    const int Mc  = B * Tc;
    const size_t a_bytes = (size_t)nmt * 34 * 32768;

    float*    h_state = (float*)d_ws;
    char*     Wblob   = (char*)d_ws + h_bytes;
    char*     Ablob   = (char*)d_ws + h_bytes + w_bytes;
    _Float16* proj    = (_Float16*)((char*)d_ws + h_bytes + w_bytes + a_bytes);

    bru_conv_w<<<12 * 32 * 256 / 256, 256, 0, stream>>>(wz, wr, wh, Wblob, D, U);

    for (int t0 = 0; t0 < T; t0 += Tc) {
        bru_conv_a<<<(Mc * 32) / 256, 256, 0, stream>>>(x, Ablob, T, D, Tc, t0, Mc);

        bru_gemm_mfma<<<3 * nmt * 4, 512, 0, stream>>>(
            Ablob, Wblob, bz, br, bh, proj, nmt, U, Mc);

        bru_scan<<<(B * U) / 256, 256, 0, stream>>>(
            proj, mz, mr, (float*)d_out, h_state, B, T, U, Tc, t0, Mc);
    }
}

// Round 17
// 551.005 us; speedup vs baseline: 1.1669x; 1.0041x over previous
//
#include <hip/hip_runtime.h>
#include <cmath>

using f16x8 = __attribute__((ext_vector_type(8))) _Float16;
using f32x4 = __attribute__((ext_vector_type(4))) float;

// ---------- helpers ----------
__device__ __forceinline__ void gld16(void* lds, const void* g) {
    __builtin_amdgcn_global_load_lds(
        (const __attribute__((address_space(1))) unsigned int*)g,
        (__attribute__((address_space(3))) unsigned int*)lds, 16, 0, 0);
}

// ========= Layouts (identical to r15) =========
// f16 2-product split: x = hi + lo (f16);  proj = hi*w + lo*w, W single f16.
// A-blob: per (mt256, kt) 32KB: 256 m-rows x 128B, hi/lo planes; slot
//   s = isLo*4 + q stored at s ^ (r&7).  kt stride padded to 34.
// W-blob: per (g, nt256, kt) 16KB: 256 u-rows x 64B; slot q at q ^ ((r>>1)&3).
// Linear global_load_lds reproduces the swizzled images; 16-row fragment
// reads measured 0 bank conflicts (r13-r16).

// ---------- convert x -> A blob ----------
__global__ __launch_bounds__(256)
void bru_conv_a(const float* __restrict__ x, char* __restrict__ Ablob,
                int T, int D, int Tc, int t0, int Mc)
{
    const int gid = blockIdx.x * 256 + threadIdx.x;   // Mc*32 threads
    const int kt = gid / Mc;
    const int m  = gid - kt * Mc;
    const int mt = m >> 8, row = m & 255;

    const long xrow = (long)(m / Tc) * T + t0 + (m % Tc);
    const float* src = x + xrow * (long)D + kt * 32;

    float v[32];
    #pragma unroll
    for (int i = 0; i < 8; ++i)
        *(float4*)&v[i * 4] = *(const float4*)(src + i * 4);

    _Float16 hi[32], lo[32];
    #pragma unroll
    for (int k = 0; k < 32; ++k) {
        hi[k] = (_Float16)v[k];
        lo[k] = (_Float16)(v[k] - (float)hi[k]);
    }

    char* base = Ablob + ((size_t)(mt * 34 + kt)) * 32768 + (size_t)row * 128;
    #pragma unroll
    for (int q = 0; q < 4; ++q) {
        _Float16 oh[8], ol[8];
        #pragma unroll
        for (int j = 0; j < 8; ++j) { oh[j] = hi[q * 8 + j]; ol[j] = lo[q * 8 + j]; }
        *(f16x8*)(base + (((q    ) ^ (row & 7)) << 4)) = *(f16x8*)oh;
        *(f16x8*)(base + (((q + 4) ^ (row & 7)) << 4)) = *(f16x8*)ol;
    }
}

// ---------- convert W (3 gates) -> W blobs (single f16) ----------
__global__ __launch_bounds__(256)
void bru_conv_w(const float* __restrict__ wz, const float* __restrict__ wr,
                const float* __restrict__ wh, char* __restrict__ Wblob,
                int D, int U)
{
    const int gid  = blockIdx.x * 256 + threadIdx.x;  // 12*32*256 threads
    const int blob = gid >> 8;            // (g*4+nt)*32 + kt
    const int row  = gid & 255;           // u within 256-col tile (coalesced)

    const int g    = blob >> 7;
    const int rest = blob & 127;
    const int nt   = rest >> 5;
    const int kt   = rest & 31;

    const float* W = (g == 0) ? wz : (g == 1) ? wr : wh;
    const int ucol = nt * 256 + row;

    char* base = Wblob + ((size_t)((g * 4 + nt) * 34 + kt)) * 16384 + (size_t)row * 64;
    #pragma unroll
    for (int q = 0; q < 4; ++q) {
        _Float16 o[8];
        #pragma unroll
        for (int j = 0; j < 8; ++j)
            o[j] = (_Float16)W[(long)(kt * 32 + q * 8 + j) * U + ucol];
        *(f16x8*)(base + ((q ^ ((row >> 1) & 3)) << 4)) = *(f16x8*)o;
    }
}

// ---------- f16 2-product MFMA GEMM, compiler-scheduled read/MFMA overlap ----------
// Block 256x256, 8 waves 4x2 (wave tile 64m x 128n -> 16 ds_reads/wave-kt),
// 16x16x32_f16.  A: 3x32KB; B: 3x16KB (144KB LDS).  Per kt:
// STAGE(kt+2) -> {8 B-reads, then per-m-frag {2 A-reads + 16 MFMA}} all in
// ONE compiler-scheduled region (fine-grained lgkmcnt -> LDS service overlaps
// MFMA issue) -> vmcnt(6) -> s_barrier.  No intra-kt pins, no lgkmcnt(0).
__global__ __launch_bounds__(512, 2)
void bru_gemm_mfma(const char* __restrict__ Ablob, const char* __restrict__ Wblob,
                   const float* __restrict__ bz, const float* __restrict__ br,
                   const float* __restrict__ bh,
                   _Float16* __restrict__ proj,
                   int nmt, int U, int Mc)
{
    __shared__ char sm[147456];   // A: 3x32KB @0 | B: 3x16KB @98304

    const int ngrid = gridDim.x;
    const int bid   = blockIdx.x;
    int lid = bid;
    if ((ngrid & 7) == 0) lid = (bid & 7) * (ngrid >> 3) + (bid >> 3);
    const int mt  = lid / 12;
    const int rem = lid - mt * 12;
    const int g   = rem >> 2;
    const int nt  = rem & 3;

    const int tid  = threadIdx.x;
    const int lane = tid & 63;
    const int w    = tid >> 6;
    const int wm   = w >> 1, wn = w & 1;   // 4x2 wave grid; wave tile 64x128
    const int l15  = lane & 15;
    const int lgrp = lane >> 4;

    const char* asrc = Ablob + (size_t)(mt * 34) * 32768;
    const char* bsrc = Wblob + (size_t)((g * 4 + nt) * 34) * 16384;
    const int st = tid * 16;

    const int abase = (wm * 64 + l15) * 128;           // + f*2048, f=0..3
    const int slotA = (lgrp ^ (l15 & 7)) << 4;         // lo at ^64
    const int bbase = 98304 + (wn * 128 + l15) * 64;   // + j*1024, j=0..7
    const int slotB = (lgrp ^ ((l15 >> 1) & 3)) << 4;

    f32x4 acc[4][8];
    #pragma unroll
    for (int i = 0; i < 4; ++i)
        #pragma unroll
        for (int j = 0; j < 8; ++j) acc[i][j] = (f32x4)0.f;

#define STAGE(kt_) do { \
    const int bb_ = (kt_) % 3; \
    _Pragma("unroll") for (int c_ = 0; c_ < 4; ++c_) \
        gld16(sm + bb_ * 32768 + c_ * 8192 + st, \
              asrc + (size_t)(kt_) * 32768 + c_ * 8192 + st); \
    _Pragma("unroll") for (int c_ = 0; c_ < 2; ++c_) \
        gld16(sm + 98304 + bb_ * 16384 + c_ * 8192 + st, \
              bsrc + (size_t)(kt_) * 16384 + c_ * 8192 + st); } while (0)

    // prologue: stage kt 0,1; wait kt0 complete (leave kt1's 6 in flight)
    STAGE(0); STAGE(1);
    __builtin_amdgcn_sched_barrier(0);
    asm volatile("s_waitcnt vmcnt(6)" ::: "memory");
    __builtin_amdgcn_sched_barrier(0);
    __builtin_amdgcn_s_barrier();

    for (int kt = 0; kt < 32; ++kt) {
        const int cb = kt % 3;

        STAGE(kt + 2);   // pads kt 32,33 exist; staged but never read

        const char* sa = sm + cb * 32768;
        const char* sb = sm + cb * 16384;   // +98304 folded into bbase

        // one scheduling region: compiler emits counted lgkmcnt so LDS
        // service of later fragments overlaps MFMA of earlier ones.
        f16x8 bf[8];
        #pragma unroll
        for (int j = 0; j < 8; ++j)
            bf[j] = *(const f16x8*)(sb + bbase + j * 1024 + slotB);
        #pragma unroll
        for (int f = 0; f < 4; ++f) {
            f16x8 ah = *(const f16x8*)(sa + abase + f * 2048 + slotA);
            f16x8 al = *(const f16x8*)(sa + abase + f * 2048 + (slotA ^ 64));
            #pragma unroll
            for (int j = 0; j < 8; ++j) {
                acc[f][j] = __builtin_amdgcn_mfma_f32_16x16x32_f16(ah, bf[j], acc[f][j], 0, 0, 0);
                acc[f][j] = __builtin_amdgcn_mfma_f32_16x16x32_f16(al, bf[j], acc[f][j], 0, 0, 0);
            }
        }

        // counted fence: leave only this kt's 6 stages outstanding ->
        // stage(kt+1) (issued last iteration) complete before next reads.
        __builtin_amdgcn_sched_barrier(0);
        asm volatile("s_waitcnt vmcnt(6)" ::: "memory");
        __builtin_amdgcn_sched_barrier(0);
        __builtin_amdgcn_s_barrier();
    }
#undef STAGE

    // epilogue: C map (proven): col=lane&15, row=lgrp*4+reg
    const float* bias = (g == 0) ? bz : (g == 1) ? br : bh;
    const int n0 = nt * 256 + wn * 128;
    float bcol[8];
    #pragma unroll
    for (int j = 0; j < 8; ++j) bcol[j] = bias[n0 + j * 16 + l15];

    _Float16* cbase = proj + (size_t)g * Mc * U + (size_t)n0 + l15;
    #pragma unroll
    for (int f = 0; f < 4; ++f) {
        #pragma unroll
        for (int reg = 0; reg < 4; ++reg) {
            const int row = mt * 256 + wm * 64 + f * 16 + lgrp * 4 + reg;
            #pragma unroll
            for (int j = 0; j < 8; ++j)
                cbase[(size_t)row * U + j * 16] = (_Float16)(acc[f][j][reg] + bcol[j]);
        }
    }
}

// ---------- scan: one thread per (b,u); 8-deep rotating register prefetch ----------
#define PF 8
__global__ __launch_bounds__(256)
void bru_scan(const _Float16* __restrict__ proj,
              const float* __restrict__ mz, const float* __restrict__ mr,
              float* __restrict__ out,
              float* __restrict__ hstate,
              int B, int T, int U, int Tc, int t0, int Mc)
{
    const int idx = blockIdx.x * blockDim.x + threadIdx.x;
    const int b = idx / U;
    const int u = idx - b * U;

    float h = (t0 == 0) ? 0.f : hstate[idx];
    const float vmz = mz[u];
    const float vmr = mr[u];

    const _Float16* pz = proj + (long)b * Tc * U + u;
    const _Float16* pr = pz + (long)Mc * U;
    const _Float16* ph = pr + (long)Mc * U;
    float* po = out + ((long)b * T + t0) * U + u;

    _Float16 fz[PF], fr[PF], fh[PF];
    #pragma unroll
    for (int i = 0; i < PF; ++i) {
        const long o = (long)((i < Tc) ? i : (Tc - 1)) * U;
        fz[i] = pz[o]; fr[i] = pr[o]; fh[i] = ph[o];
    }

    for (int t = 0; t < Tc; t += PF) {
        #pragma unroll
        for (int i = 0; i < PF; ++i) {
            const float xz = (float)fz[i];
            const float xr = (float)fr[i];
            const float xh = (float)fh[i];
            {
                int tn = t + i + PF; if (tn > Tc - 1) tn = Tc - 1;
                const long o = (long)tn * U;
                fz[i] = pz[o]; fr[i] = pr[o]; fh[i] = ph[o];
            }
            const float e2r = __expf(2.f * (xr + h * vmr));
            const float rr  = 2.f - 2.f / (e2r + 1.f);             // tanh(.)+1
            const float zz  = 1.f / (1.f + __expf(-(xz + h * vmz)));
            const float e2h = __expf(2.f * (xh + rr * h));
            const float hh  = 1.f - 2.f / (e2h + 1.f);             // tanh(.)
            h = (1.f - zz) * hh + zz * h;
            if (t + i < Tc) po[(long)(t + i) * U] = h;
        }
    }
    hstate[idx] = h;
}

// ---------- launch ----------
extern "C" void kernel_launch(void* const* d_in, const int* in_sizes, int n_in,
                              void* d_out, int out_size, void* d_ws, size_t ws_size,
                              hipStream_t stream)
{
    const float* x  = (const float*)d_in[0];
    const float* wz = (const float*)d_in[1];
    const float* wr = (const float*)d_in[2];
    const float* wh = (const float*)d_in[3];
    const float* mz = (const float*)d_in[4];
    const float* mr = (const float*)d_in[5];
    const float* bz = (const float*)d_in[6];
    const float* br = (const float*)d_in[7];
    const float* bh = (const float*)d_in[8];

    const int B = 64, T = 512, D = 1024, U = 1024;

    const size_t h_bytes = (size_t)B * U * sizeof(float);
    const size_t w_bytes = (size_t)12 * 34 * 16384;   // 6.68 MB incl. pad

    int Tc = T;
    while (Tc > 4) {
        const int nmt_ = B * Tc / 256;
        const size_t a_bytes_ = (size_t)nmt_ * 34 * 32768;
        const size_t p_bytes_ = 3ull * B * Tc * U * sizeof(_Float16);
        if (h_bytes + w_bytes + a_bytes_ + p_bytes_ <= ws_size) break;
        Tc >>= 1;
    }
    const int nmt = B * Tc / 256;
    const int Mc  = B * Tc;
    const size_t a_bytes = (size_t)nmt * 34 * 32768;

    float*    h_state = (float*)d_ws;
    char*     Wblob   = (char*)d_ws + h_bytes;
    char*     Ablob   = (char*)d_ws + h_bytes + w_bytes;
    _Float16* proj    = (_Float16*)((char*)d_ws + h_bytes + w_bytes + a_bytes);

    bru_conv_w<<<12 * 32 * 256 / 256, 256, 0, stream>>>(wz, wr, wh, Wblob, D, U);

    for (int t0 = 0; t0 < T; t0 += Tc) {
        bru_conv_a<<<(Mc * 32) / 256, 256, 0, stream>>>(x, Ablob, T, D, Tc, t0, Mc);

        bru_gemm_mfma<<<3 * nmt * 4, 512, 0, stream>>>(
            Ablob, Wblob, bz, br, bh, proj, nmt, U, Mc);

        bru_scan<<<(B * U) / 256, 256, 0, stream>>>(
            proj, mz, mr, (float*)d_out, h_state, B, T, U, Tc, t0, Mc);
    }
}

// Round 18
// 549.141 us; speedup vs baseline: 1.1709x; 1.0034x over previous
//
#include <hip/hip_runtime.h>
#include <cmath>

using f16x8 = __attribute__((ext_vector_type(8))) _Float16;
using f32x4 = __attribute__((ext_vector_type(4))) float;

// ---------- helpers ----------
__device__ __forceinline__ void gld16(void* lds, const void* g) {
    __builtin_amdgcn_global_load_lds(
        (const __attribute__((address_space(1))) unsigned int*)g,
        (__attribute__((address_space(3))) unsigned int*)lds, 16, 0, 0);
}

// ========= Layouts (identical to r15/r17) =========
// f16 2-product split: x = hi + lo (f16);  proj = hi*w + lo*w, W single f16.
// A-blob: per (mt256, kt) 32KB: 256 m-rows x 128B, hi/lo planes; slot
//   s = isLo*4 + q stored at s ^ (r&7).  kt stride padded to 34.
// W-blob: per (g, nt256, kt) 16KB: 256 u-rows x 64B; slot q at q ^ ((r>>1)&3).
// Linear global_load_lds reproduces the swizzled images; 16-row fragment
// reads measured 0 bank conflicts (r13-r17).

// ---------- convert x -> A blob ----------
__global__ __launch_bounds__(256)
void bru_conv_a(const float* __restrict__ x, char* __restrict__ Ablob,
                int T, int D, int Tc, int t0, int Mc)
{
    const int gid = blockIdx.x * 256 + threadIdx.x;   // Mc*32 threads
    const int kt = gid / Mc;
    const int m  = gid - kt * Mc;
    const int mt = m >> 8, row = m & 255;

    const long xrow = (long)(m / Tc) * T + t0 + (m % Tc);
    const float* src = x + xrow * (long)D + kt * 32;

    float v[32];
    #pragma unroll
    for (int i = 0; i < 8; ++i)
        *(float4*)&v[i * 4] = *(const float4*)(src + i * 4);

    _Float16 hi[32], lo[32];
    #pragma unroll
    for (int k = 0; k < 32; ++k) {
        hi[k] = (_Float16)v[k];
        lo[k] = (_Float16)(v[k] - (float)hi[k]);
    }

    char* base = Ablob + ((size_t)(mt * 34 + kt)) * 32768 + (size_t)row * 128;
    #pragma unroll
    for (int q = 0; q < 4; ++q) {
        _Float16 oh[8], ol[8];
        #pragma unroll
        for (int j = 0; j < 8; ++j) { oh[j] = hi[q * 8 + j]; ol[j] = lo[q * 8 + j]; }
        *(f16x8*)(base + (((q    ) ^ (row & 7)) << 4)) = *(f16x8*)oh;
        *(f16x8*)(base + (((q + 4) ^ (row & 7)) << 4)) = *(f16x8*)ol;
    }
}

// ---------- convert W (3 gates) -> W blobs (single f16) ----------
__global__ __launch_bounds__(256)
void bru_conv_w(const float* __restrict__ wz, const float* __restrict__ wr,
                const float* __restrict__ wh, char* __restrict__ Wblob,
                int D, int U)
{
    const int gid  = blockIdx.x * 256 + threadIdx.x;  // 12*32*256 threads
    const int blob = gid >> 8;            // (g*4+nt)*32 + kt
    const int row  = gid & 255;           // u within 256-col tile (coalesced)

    const int g    = blob >> 7;
    const int rest = blob & 127;
    const int nt   = rest >> 5;
    const int kt   = rest & 31;

    const float* W = (g == 0) ? wz : (g == 1) ? wr : wh;
    const int ucol = nt * 256 + row;

    char* base = Wblob + ((size_t)((g * 4 + nt) * 34 + kt)) * 16384 + (size_t)row * 64;
    #pragma unroll
    for (int q = 0; q < 4; ++q) {
        _Float16 o[8];
        #pragma unroll
        for (int j = 0; j < 8; ++j)
            o[j] = (_Float16)W[(long)(kt * 32 + q * 8 + j) * U + ucol];
        *(f16x8*)(base + ((q ^ ((row >> 1) & 3)) << 4)) = *(f16x8*)o;
    }
}

// ---------- f16 2-product MFMA GEMM, dependency-wavefront interleave ----------
// Block 256x256, 8 waves 4x2 (wave tile 64m x 128n), 16x16x32_f16.
// A: 3x32KB; B: 3x16KB (144KB LDS), distance-2 stage, vmcnt(6), 1 barrier/kt.
// Inner kt: reads issued <=2 at a time, one sched_barrier-group ahead of the
// MFMAs that consume them (first MFMA after only 3 reads) -> the LDS FIFO
// stays shallow and services under the MFMA stream instead of before it
// (r15-r17 measured cost = MFMA + LDS as an exact SUM; this overlaps them).
__global__ __launch_bounds__(512, 2)
void bru_gemm_mfma(const char* __restrict__ Ablob, const char* __restrict__ Wblob,
                   const float* __restrict__ bz, const float* __restrict__ br,
                   const float* __restrict__ bh,
                   _Float16* __restrict__ proj,
                   int nmt, int U, int Mc)
{
    __shared__ char sm[147456];   // A: 3x32KB @0 | B: 3x16KB @98304

    const int ngrid = gridDim.x;
    const int bid   = blockIdx.x;
    int lid = bid;
    if ((ngrid & 7) == 0) lid = (bid & 7) * (ngrid >> 3) + (bid >> 3);
    const int mt  = lid / 12;
    const int rem = lid - mt * 12;
    const int g   = rem >> 2;
    const int nt  = rem & 3;

    const int tid  = threadIdx.x;
    const int lane = tid & 63;
    const int w    = tid >> 6;
    const int wm   = w >> 1, wn = w & 1;   // 4x2 wave grid; wave tile 64x128
    const int l15  = lane & 15;
    const int lgrp = lane >> 4;

    const char* asrc = Ablob + (size_t)(mt * 34) * 32768;
    const char* bsrc = Wblob + (size_t)((g * 4 + nt) * 34) * 16384;
    const int st = tid * 16;

    const int abase = (wm * 64 + l15) * 128;           // + f*2048, f=0..3
    const int slotA = (lgrp ^ (l15 & 7)) << 4;         // lo at ^64
    const int bbase = 98304 + (wn * 128 + l15) * 64;   // + j*1024, j=0..7
    const int slotB = (lgrp ^ ((l15 >> 1) & 3)) << 4;

    f32x4 acc[4][8];
    #pragma unroll
    for (int i = 0; i < 4; ++i)
        #pragma unroll
        for (int j = 0; j < 8; ++j) acc[i][j] = (f32x4)0.f;

#define STAGE(kt_) do { \
    const int bb_ = (kt_) % 3; \
    _Pragma("unroll") for (int c_ = 0; c_ < 4; ++c_) \
        gld16(sm + bb_ * 32768 + c_ * 8192 + st, \
              asrc + (size_t)(kt_) * 32768 + c_ * 8192 + st); \
    _Pragma("unroll") for (int c_ = 0; c_ < 2; ++c_) \
        gld16(sm + 98304 + bb_ * 16384 + c_ * 8192 + st, \
              bsrc + (size_t)(kt_) * 16384 + c_ * 8192 + st); } while (0)

    // prologue: stage kt 0,1; wait kt0 complete (leave kt1's 6 in flight)
    STAGE(0); STAGE(1);
    __builtin_amdgcn_sched_barrier(0);
    asm volatile("s_waitcnt vmcnt(6)" ::: "memory");
    __builtin_amdgcn_sched_barrier(0);
    __builtin_amdgcn_s_barrier();

#define SB  __builtin_amdgcn_sched_barrier(0)
#define RD_B(j_) bf[j_] = *(const f16x8*)(sb + bbase + (j_) * 1024 + slotB)
#define RD_A(f_) do { \
    ah[f_] = *(const f16x8*)(sa + abase + (f_) * 2048 + slotA); \
    al[f_] = *(const f16x8*)(sa + abase + (f_) * 2048 + (slotA ^ 64)); } while (0)
#define MM(f_, j_) do { \
    acc[f_][j_] = __builtin_amdgcn_mfma_f32_16x16x32_f16(ah[f_], bf[j_], acc[f_][j_], 0, 0, 0); \
    acc[f_][j_] = __builtin_amdgcn_mfma_f32_16x16x32_f16(al[f_], bf[j_], acc[f_][j_], 0, 0, 0); } while (0)

    for (int kt = 0; kt < 32; ++kt) {
        const int cb = kt % 3;
        const char* sa = sm + cb * 32768;
        const char* sb = sm + cb * 16384;   // +98304 folded into bbase

        STAGE(kt + 2);   // pads kt 32,33 exist; staged but never read

        f16x8 ah[4], al[4], bf[8];
        // dependency-wavefront: each SB-group's reads feed the NEXT group's
        // MFMAs; MFMA groups grow 2 -> 8 as operands become available.
        RD_B(0); RD_A(0);                            SB;
        MM(0,0);                   RD_B(1);          SB;
        MM(0,1);                   RD_A(1);          SB;
        MM(1,0); MM(1,1);          RD_B(2);          SB;
        MM(0,2); MM(1,2);          RD_A(2);          SB;
        MM(2,0); MM(2,1); MM(2,2); RD_B(3);          SB;
        MM(0,3); MM(1,3); MM(2,3); RD_A(3);          SB;
        MM(3,0); MM(3,1); MM(3,2); MM(3,3); RD_B(4); SB;
        MM(0,4); MM(1,4); MM(2,4); MM(3,4); RD_B(5); SB;
        MM(0,5); MM(1,5); MM(2,5); MM(3,5); RD_B(6); SB;
        MM(0,6); MM(1,6); MM(2,6); MM(3,6); RD_B(7); SB;
        MM(0,7); MM(1,7); MM(2,7); MM(3,7);

        // counted fence: leave only this kt's 6 stages outstanding ->
        // stage(kt+1) (issued last iteration) complete before next reads.
        __builtin_amdgcn_sched_barrier(0);
        asm volatile("s_waitcnt vmcnt(6)" ::: "memory");
        __builtin_amdgcn_sched_barrier(0);
        __builtin_amdgcn_s_barrier();
    }
#undef STAGE
#undef SB
#undef RD_B
#undef RD_A
#undef MM

    // epilogue: C map (proven): col=lane&15, row=lgrp*4+reg
    const float* bias = (g == 0) ? bz : (g == 1) ? br : bh;
    const int n0 = nt * 256 + wn * 128;
    float bcol[8];
    #pragma unroll
    for (int j = 0; j < 8; ++j) bcol[j] = bias[n0 + j * 16 + l15];

    _Float16* cbase = proj + (size_t)g * Mc * U + (size_t)n0 + l15;
    #pragma unroll
    for (int f = 0; f < 4; ++f) {
        #pragma unroll
        for (int reg = 0; reg < 4; ++reg) {
            const int row = mt * 256 + wm * 64 + f * 16 + lgrp * 4 + reg;
            #pragma unroll
            for (int j = 0; j < 8; ++j)
                cbase[(size_t)row * U + j * 16] = (_Float16)(acc[f][j][reg] + bcol[j]);
        }
    }
}

// ---------- scan: one thread per (b,u); 8-deep rotating register prefetch ----------
#define PF 8
__global__ __launch_bounds__(256)
void bru_scan(const _Float16* __restrict__ proj,
              const float* __restrict__ mz, const float* __restrict__ mr,
              float* __restrict__ out,
              float* __restrict__ hstate,
              int B, int T, int U, int Tc, int t0, int Mc)
{
    const int idx = blockIdx.x * blockDim.x + threadIdx.x;
    const int b = idx / U;
    const int u = idx - b * U;

    float h = (t0 == 0) ? 0.f : hstate[idx];
    const float vmz = mz[u];
    const float vmr = mr[u];

    const _Float16* pz = proj + (long)b * Tc * U + u;
    const _Float16* pr = pz + (long)Mc * U;
    const _Float16* ph = pr + (long)Mc * U;
    float* po = out + ((long)b * T + t0) * U + u;

    _Float16 fz[PF], fr[PF], fh[PF];
    #pragma unroll
    for (int i = 0; i < PF; ++i) {
        const long o = (long)((i < Tc) ? i : (Tc - 1)) * U;
        fz[i] = pz[o]; fr[i] = pr[o]; fh[i] = ph[o];
    }

    for (int t = 0; t < Tc; t += PF) {
        #pragma unroll
        for (int i = 0; i < PF; ++i) {
            const float xz = (float)fz[i];
            const float xr = (float)fr[i];
            const float xh = (float)fh[i];
            {
                int tn = t + i + PF; if (tn > Tc - 1) tn = Tc - 1;
                const long o = (long)tn * U;
                fz[i] = pz[o]; fr[i] = pr[o]; fh[i] = ph[o];
            }
            const float e2r = __expf(2.f * (xr + h * vmr));
            const float rr  = 2.f - 2.f / (e2r + 1.f);             // tanh(.)+1
            const float zz  = 1.f / (1.f + __expf(-(xz + h * vmz)));
            const float e2h = __expf(2.f * (xh + rr * h));
            const float hh  = 1.f - 2.f / (e2h + 1.f);             // tanh(.)
            h = (1.f - zz) * hh + zz * h;
            if (t + i < Tc) po[(long)(t + i) * U] = h;
        }
    }
    hstate[idx] = h;
}

// ---------- launch ----------
extern "C" void kernel_launch(void* const* d_in, const int* in_sizes, int n_in,
                              void* d_out, int out_size, void* d_ws, size_t ws_size,
                              hipStream_t stream)
{
    const float* x  = (const float*)d_in[0];
    const float* wz = (const float*)d_in[1];
    const float* wr = (const float*)d_in[2];
    const float* wh = (const float*)d_in[3];
    const float* mz = (const float*)d_in[4];
    const float* mr = (const float*)d_in[5];
    const float* bz = (const float*)d_in[6];
    const float* br = (const float*)d_in[7];
    const float* bh = (const float*)d_in[8];

    const int B = 64, T = 512, D = 1024, U = 1024;

    const size_t h_bytes = (size_t)B * U * sizeof(float);
    const size_t w_bytes = (size_t)12 * 34 * 16384;   // 6.68 MB incl. pad

    int Tc = T;
    while (Tc > 4) {
        const int nmt_ = B * Tc / 256;
        const size_t a_bytes_ = (size_t)nmt_ * 34 * 32768;
        const size_t p_bytes_ = 3ull * B * Tc * U * sizeof(_Float16);
        if (h_bytes + w_bytes + a_bytes_ + p_bytes_ <= ws_size) break;
        Tc >>= 1;
    }
    const int nmt = B * Tc / 256;
    const int Mc  = B * Tc;
    const size_t a_bytes = (size_t)nmt * 34 * 32768;

    float*    h_state = (float*)d_ws;
    char*     Wblob   = (char*)d_ws + h_bytes;
    char*     Ablob   = (char*)d_ws + h_bytes + w_bytes;
    _Float16* proj    = (_Float16*)((char*)d_ws + h_bytes + w_bytes + a_bytes);

    bru_conv_w<<<12 * 32 * 256 / 256, 256, 0, stream>>>(wz, wr, wh, Wblob, D, U);

    for (int t0 = 0; t0 < T; t0 += Tc) {
        bru_conv_a<<<(Mc * 32) / 256, 256, 0, stream>>>(x, Ablob, T, D, Tc, t0, Mc);

        bru_gemm_mfma<<<3 * nmt * 4, 512, 0, stream>>>(
            Ablob, Wblob, bz, br, bh, proj, nmt, U, Mc);

        bru_scan<<<(B * U) / 256, 256, 0, stream>>>(
            proj, mz, mr, (float*)d_out, h_state, B, T, U, Tc, t0, Mc);
    }
}

// Round 19
// 541.852 us; speedup vs baseline: 1.1866x; 1.0135x over previous
//
#include <hip/hip_runtime.h>
#include <cmath>

using f16x8 = __attribute__((ext_vector_type(8))) _Float16;
using f32x4 = __attribute__((ext_vector_type(4))) float;

// ---------- helpers ----------
__device__ __forceinline__ void gld16(void* lds, const void* g) {
    __builtin_amdgcn_global_load_lds(
        (const __attribute__((address_space(1))) unsigned int*)g,
        (__attribute__((address_space(3))) unsigned int*)lds, 16, 0, 0);
}

// ========= Layouts =========
// f16 2-product split: x = hi + lo (f16);  proj = hi*w + lo*w, W single f16.
// A-blob: per (mt128, kt) 16KB: 128 m-rows x 128B, hi/lo planes; slot
//   s = isLo*4 + q stored at s ^ (r&7)  (proven 0-conflict).  kt stride 34.
// W-blob: per (g, nt256, kt) 16KB: 256 u-rows x 64B; slot q at q ^ ((r>>1)&3).
//   kt stride 34.  Linear global_load_lds reproduces the swizzled images.

// ---------- convert x -> A blob ----------
__global__ __launch_bounds__(256)
void bru_conv_a(const float* __restrict__ x, char* __restrict__ Ablob,
                int T, int D, int Tc, int t0, int Mc)
{
    const int gid = blockIdx.x * 256 + threadIdx.x;   // Mc*32 threads
    const int kt = gid / Mc;
    const int m  = gid - kt * Mc;
    const int mt = m >> 7, row = m & 127;

    const long xrow = (long)(m / Tc) * T + t0 + (m % Tc);
    const float* src = x + xrow * (long)D + kt * 32;

    float v[32];
    #pragma unroll
    for (int i = 0; i < 8; ++i)
        *(float4*)&v[i * 4] = *(const float4*)(src + i * 4);

    _Float16 hi[32], lo[32];
    #pragma unroll
    for (int k = 0; k < 32; ++k) {
        hi[k] = (_Float16)v[k];
        lo[k] = (_Float16)(v[k] - (float)hi[k]);
    }

    char* base = Ablob + ((size_t)(mt * 34 + kt)) * 16384 + (size_t)row * 128;
    #pragma unroll
    for (int q = 0; q < 4; ++q) {
        _Float16 oh[8], ol[8];
        #pragma unroll
        for (int j = 0; j < 8; ++j) { oh[j] = hi[q * 8 + j]; ol[j] = lo[q * 8 + j]; }
        *(f16x8*)(base + (((q    ) ^ (row & 7)) << 4)) = *(f16x8*)oh;
        *(f16x8*)(base + (((q + 4) ^ (row & 7)) << 4)) = *(f16x8*)ol;
    }
}

// ---------- convert W (3 gates) -> W blobs (single f16) ----------
__global__ __launch_bounds__(256)
void bru_conv_w(const float* __restrict__ wz, const float* __restrict__ wr,
                const float* __restrict__ wh, char* __restrict__ Wblob,
                int D, int U)
{
    const int gid  = blockIdx.x * 256 + threadIdx.x;  // 12*32*256 threads
    const int blob = gid >> 8;            // (g*4+nt)*32 + kt
    const int row  = gid & 255;           // u within 256-col tile (coalesced)

    const int g    = blob >> 7;
    const int rest = blob & 127;
    const int nt   = rest >> 5;
    const int kt   = rest & 31;

    const float* W = (g == 0) ? wz : (g == 1) ? wr : wh;
    const int ucol = nt * 256 + row;

    char* base = Wblob + ((size_t)((g * 4 + nt) * 34 + kt)) * 16384 + (size_t)row * 64;
    #pragma unroll
    for (int q = 0; q < 4; ++q) {
        _Float16 o[8];
        #pragma unroll
        for (int j = 0; j < 8; ++j)
            o[j] = (_Float16)W[(long)(kt * 32 + q * 8 + j) * U + ucol];
        *(f16x8*)(base + ((q ^ ((row >> 1) & 3)) << 4)) = *(f16x8*)o;
    }
}

// ---------- f16 2-product MFMA GEMM, 2 independent blocks/CU ----------
// Block tile 128x256, 256 threads = 4 waves 2x2 (wave tile 64m x 128n),
// 16x16x32_f16.  LDS 64KB: A 2x16KB + B 2x16KB double buffer -> 2 blocks/CU.
// The two co-resident blocks share no barrier, so one block's MFMA stream
// covers the other's LDS read burst + staging drain (r13 evidence: async
// blocks reach the max() of the pipes; r15-r18's barrier-locked 8-wave
// blocks were stuck at the sum).
__global__ __launch_bounds__(256, 2)
void bru_gemm_mfma(const char* __restrict__ Ablob, const char* __restrict__ Wblob,
                   const float* __restrict__ bz, const float* __restrict__ br,
                   const float* __restrict__ bh,
                   _Float16* __restrict__ proj,
                   int nmt, int U, int Mc)
{
    __shared__ char sm[65536];   // A: 2x16KB @0 | B: 2x16KB @32768

    const int ngrid = gridDim.x;
    const int bid   = blockIdx.x;
    int lid = bid;
    if ((ngrid & 7) == 0) lid = (bid & 7) * (ngrid >> 3) + (bid >> 3);
    const int mt  = lid / 12;
    const int rem = lid - mt * 12;
    const int g   = rem >> 2;
    const int nt  = rem & 3;

    const int tid  = threadIdx.x;
    const int lane = tid & 63;
    const int w    = tid >> 6;
    const int wm   = w >> 1, wn = w & 1;   // 2x2 wave grid; wave tile 64x128
    const int l15  = lane & 15;
    const int lgrp = lane >> 4;

    const char* asrc = Ablob + (size_t)(mt * 34) * 16384;
    const char* bsrc = Wblob + (size_t)((g * 4 + nt) * 34) * 16384;
    const int st = tid * 16;

    const int abase = (wm * 64 + l15) * 128;           // + f*2048, f=0..3
    const int slotA = (lgrp ^ (l15 & 7)) << 4;         // lo at ^64
    const int bbase = 32768 + (wn * 128 + l15) * 64;   // + j*1024, j=0..7
    const int slotB = (lgrp ^ ((l15 >> 1) & 3)) << 4;

    f32x4 acc[4][8];
    #pragma unroll
    for (int i = 0; i < 4; ++i)
        #pragma unroll
        for (int j = 0; j < 8; ++j) acc[i][j] = (f32x4)0.f;

#define STAGE(kt_) do { \
    const int bb_ = (kt_) & 1; \
    _Pragma("unroll") for (int c_ = 0; c_ < 4; ++c_) \
        gld16(sm + bb_ * 16384 + c_ * 4096 + st, \
              asrc + (size_t)(kt_) * 16384 + c_ * 4096 + st); \
    _Pragma("unroll") for (int c_ = 0; c_ < 4; ++c_) \
        gld16(sm + 32768 + bb_ * 16384 + c_ * 4096 + st, \
              bsrc + (size_t)(kt_) * 16384 + c_ * 4096 + st); } while (0)

    // prologue: stage kt=0, drain
    STAGE(0);
    __syncthreads();

    for (int kt = 0; kt < 32; ++kt) {
        STAGE(kt + 1);   // pad kt=32 exists (stride 34); staged, never read

        const char* sa = sm + (kt & 1) * 16384;
        const char* sb = sm + (kt & 1) * 16384;   // +32768 folded into bbase

        // one compiler-scheduled region: counted lgkmcnt overlaps LDS
        // service with MFMA issue within the wave; cross-block async
        // covers the rest.
        f16x8 bf[8];
        #pragma unroll
        for (int j = 0; j < 8; ++j)
            bf[j] = *(const f16x8*)(sb + bbase + j * 1024 + slotB);
        #pragma unroll
        for (int f = 0; f < 4; ++f) {
            f16x8 ah = *(const f16x8*)(sa + abase + f * 2048 + slotA);
            f16x8 al = *(const f16x8*)(sa + abase + f * 2048 + (slotA ^ 64));
            #pragma unroll
            for (int j = 0; j < 8; ++j) {
                acc[f][j] = __builtin_amdgcn_mfma_f32_16x16x32_f16(ah, bf[j], acc[f][j], 0, 0, 0);
                acc[f][j] = __builtin_amdgcn_mfma_f32_16x16x32_f16(al, bf[j], acc[f][j], 0, 0, 0);
            }
        }

        __syncthreads();   // drain stage(kt+1) + readers done; swap buffers
    }
#undef STAGE

    // epilogue: C map (proven): col=lane&15, row=lgrp*4+reg
    const float* bias = (g == 0) ? bz : (g == 1) ? br : bh;
    const int n0 = nt * 256 + wn * 128;
    float bcol[8];
    #pragma unroll
    for (int j = 0; j < 8; ++j) bcol[j] = bias[n0 + j * 16 + l15];

    _Float16* cbase = proj + (size_t)g * Mc * U + (size_t)n0 + l15;
    #pragma unroll
    for (int f = 0; f < 4; ++f) {
        #pragma unroll
        for (int reg = 0; reg < 4; ++reg) {
            const int row = mt * 128 + wm * 64 + f * 16 + lgrp * 4 + reg;
            #pragma unroll
            for (int j = 0; j < 8; ++j)
                cbase[(size_t)row * U + j * 16] = (_Float16)(acc[f][j][reg] + bcol[j]);
        }
    }
}

// ---------- scan: one thread per (b,u); 8-deep rotating register prefetch ----------
#define PF 8
__global__ __launch_bounds__(256)
void bru_scan(const _Float16* __restrict__ proj,
              const float* __restrict__ mz, const float* __restrict__ mr,
              float* __restrict__ out,
              float* __restrict__ hstate,
              int B, int T, int U, int Tc, int t0, int Mc)
{
    const int idx = blockIdx.x * blockDim.x + threadIdx.x;
    const int b = idx / U;
    const int u = idx - b * U;

    float h = (t0 == 0) ? 0.f : hstate[idx];
    const float vmz = mz[u];
    const float vmr = mr[u];

    const _Float16* pz = proj + (long)b * Tc * U + u;
    const _Float16* pr = pz + (long)Mc * U;
    const _Float16* ph = pr + (long)Mc * U;
    float* po = out + ((long)b * T + t0) * U + u;

    _Float16 fz[PF], fr[PF], fh[PF];
    #pragma unroll
    for (int i = 0; i < PF; ++i) {
        const long o = (long)((i < Tc) ? i : (Tc - 1)) * U;
        fz[i] = pz[o]; fr[i] = pr[o]; fh[i] = ph[o];
    }

    for (int t = 0; t < Tc; t += PF) {
        #pragma unroll
        for (int i = 0; i < PF; ++i) {
            const float xz = (float)fz[i];
            const float xr = (float)fr[i];
            const float xh = (float)fh[i];
            {
                int tn = t + i + PF; if (tn > Tc - 1) tn = Tc - 1;
                const long o = (long)tn * U;
                fz[i] = pz[o]; fr[i] = pr[o]; fh[i] = ph[o];
            }
            const float e2r = __expf(2.f * (xr + h * vmr));
            const float rr  = 2.f - 2.f / (e2r + 1.f);             // tanh(.)+1
            const float zz  = 1.f / (1.f + __expf(-(xz + h * vmz)));
            const float e2h = __expf(2.f * (xh + rr * h));
            const float hh  = 1.f - 2.f / (e2h + 1.f);             // tanh(.)
            h = (1.f - zz) * hh + zz * h;
            if (t + i < Tc) po[(long)(t + i) * U] = h;
        }
    }
    hstate[idx] = h;
}

// ---------- launch ----------
extern "C" void kernel_launch(void* const* d_in, const int* in_sizes, int n_in,
                              void* d_out, int out_size, void* d_ws, size_t ws_size,
                              hipStream_t stream)
{
    const float* x  = (const float*)d_in[0];
    const float* wz = (const float*)d_in[1];
    const float* wr = (const float*)d_in[2];
    const float* wh = (const float*)d_in[3];
    const float* mz = (const float*)d_in[4];
    const float* mr = (const float*)d_in[5];
    const float* bz = (const float*)d_in[6];
    const float* br = (const float*)d_in[7];
    const float* bh = (const float*)d_in[8];

    const int B = 64, T = 512, D = 1024, U = 1024;

    const size_t h_bytes = (size_t)B * U * sizeof(float);
    const size_t w_bytes = (size_t)12 * 34 * 16384;   // 6.68 MB incl. pad

    int Tc = T;
    while (Tc > 4) {
        const int nmt_ = B * Tc / 128;
        const size_t a_bytes_ = (size_t)nmt_ * 34 * 16384;
        const size_t p_bytes_ = 3ull * B * Tc * U * sizeof(_Float16);
        if (h_bytes + w_bytes + a_bytes_ + p_bytes_ <= ws_size) break;
        Tc >>= 1;
    }
    const int nmt = B * Tc / 128;
    const int Mc  = B * Tc;
    const size_t a_bytes = (size_t)nmt * 34 * 16384;

    float*    h_state = (float*)d_ws;
    char*     Wblob   = (char*)d_ws + h_bytes;
    char*     Ablob   = (char*)d_ws + h_bytes + w_bytes;
    _Float16* proj    = (_Float16*)((char*)d_ws + h_bytes + w_bytes + a_bytes);

    bru_conv_w<<<12 * 32 * 256 / 256, 256, 0, stream>>>(wz, wr, wh, Wblob, D, U);

    for (int t0 = 0; t0 < T; t0 += Tc) {
        bru_conv_a<<<(Mc * 32) / 256, 256, 0, stream>>>(x, Ablob, T, D, Tc, t0, Mc);

        bru_gemm_mfma<<<3 * nmt * 4, 256, 0, stream>>>(
            Ablob, Wblob, bz, br, bh, proj, nmt, U, Mc);

        bru_scan<<<(B * U) / 256, 256, 0, stream>>>(
            proj, mz, mr, (float*)d_out, h_state, B, T, U, Tc, t0, Mc);
    }
}